// Round 2
// baseline (17328.267 us; speedup 1.0000x reference)
//
#include <hip/hip_runtime.h>
#include <hip/hip_bf16.h>
#include <math.h>

#define EMBED 768
#define NTOK  1024   // 32*32
#define BATCH 4
#define NHEAD 12
#define HD    64
#define MLPD  3072
#define M_ROWS 4096  // BATCH*NTOK

// ---------------- patch embed: conv16x16 stride16 + bias + pos_embed -> h (fp32) ----
__global__ __launch_bounds__(256)
void patch_embed(const float* __restrict__ x,     // (4,3,512,512)
                 const float* __restrict__ w,     // (768,3,16,16)
                 const float* __restrict__ bias,  // (768)
                 const float* __restrict__ pos,   // (1,32,32,768)
                 float* __restrict__ h)           // (4096,768)
{
    int p  = blockIdx.x;            // b*1024 + gh*32 + gw
    int b  = p >> 10;
    int n  = p & 1023;
    int gh = n >> 5, gw = n & 31;
    int tid = threadIdx.x;

    __shared__ float patch[768];    // ci*256 + kh*16 + kw
    for (int i = tid; i < 768; i += 256) {
        int ci = i >> 8, r = i & 255, kh = r >> 4, kw = r & 15;
        patch[i] = x[(((size_t)b*3 + ci)*512 + (gh*16 + kh))*512 + gw*16 + kw];
    }
    __syncthreads();

    for (int c = tid; c < 768; c += 256) {
        const float* wr = w + (size_t)c*768;
        float acc = 0.f;
        for (int k = 0; k < 768; ++k) acc += patch[k] * wr[k];
        acc += bias[c] + pos[(size_t)n*768 + c];
        h[(size_t)p*768 + c] = acc;
    }
}

// ---------------- layernorm: row of 768, fp32 in, fp32 out --------------------------
__global__ __launch_bounds__(256)
void layernorm(const float* __restrict__ in,
               const float* __restrict__ w,
               const float* __restrict__ b,
               float* __restrict__ out)
{
    int row = blockIdx.x;
    const float* xr = in + (size_t)row*768;
    int tid = threadIdx.x;
    float s = 0.f, ss = 0.f;
    for (int i = tid; i < 768; i += 256) { float v = xr[i]; s += v; ss += v*v; }
    __shared__ float rs[256], rss[256];
    rs[tid] = s; rss[tid] = ss; __syncthreads();
    for (int o = 128; o > 0; o >>= 1) {
        if (tid < o) { rs[tid] += rs[tid+o]; rss[tid] += rss[tid+o]; }
        __syncthreads();
    }
    float mean = rs[0] * (1.f/768.f);
    float var  = rss[0] * (1.f/768.f) - mean*mean;
    float inv  = rsqrtf(var + 1e-5f);
    for (int i = tid; i < 768; i += 256)
        out[(size_t)row*768 + i] = (xr[i]-mean)*inv*w[i] + b[i];
}

// ---------------- GEMM: C[M,N] = act(A[M,K]*W[K,N] + bias) (+res) -------------------
// A fp32 (ws), W/bias fp32 (inputs), res/C fp32 (ws). 16x16 LDS tiles, 1 out/thread.
__global__ __launch_bounds__(256)
void gemm_tiled(const float* __restrict__ A,
                const float* __restrict__ W,
                const float* __restrict__ bias,
                const float* __restrict__ res,
                float* __restrict__ C,
                int M, int N, int K, int dogelu)
{
    __shared__ float As[16][17];
    __shared__ float Ws[16][17];
    int tx = threadIdx.x, ty = threadIdx.y;
    int m = blockIdx.y*16 + ty;
    int n = blockIdx.x*16 + tx;
    float acc = 0.f;
    for (int k0 = 0; k0 < K; k0 += 16) {
        As[ty][tx] = A[(size_t)m*K + k0 + tx];
        Ws[ty][tx] = W[(size_t)(k0+ty)*N + n];
        __syncthreads();
        #pragma unroll
        for (int kk = 0; kk < 16; ++kk) acc += As[ty][kk] * Ws[kk][tx];
        __syncthreads();
    }
    acc += bias[n];
    if (dogelu) acc = 0.5f*acc*(1.f + erff(acc*0.70710678118f));
    if (res) acc += res[(size_t)m*N + n];
    C[(size_t)m*N + n] = acc;
}

// ---------------- fused attention with decomposed rel-pos ---------------------------
// One block handles 8 consecutive queries (same qh row) for one (b,head).
// grid = 48*128 blocks, 256 threads.
__global__ __launch_bounds__(256)
void attention(const float* __restrict__ qkv,     // (4,1024,2304) fp32
               const float* __restrict__ rph,     // (63,64) this layer
               const float* __restrict__ rpw,     // (63,64)
               float* __restrict__ out)           // (4,1024,768) fp32
{
    int bh   = blockIdx.x >> 7;       // 0..47
    int qblk = blockIdx.x & 127;      // 0..127
    int b    = bh / NHEAD;
    int head = bh % NHEAD;
    int n0   = qblk * 8;
    int qh   = n0 >> 5;               // same for all 8 queries
    int qw0  = n0 & 31;
    int tid  = threadIdx.x;

    __shared__ float qv[8][64];
    __shared__ float relh[8][32];
    __shared__ float relw[8][32];
    __shared__ float sc[8][1024];
    __shared__ float red[256];
    __shared__ float part[4][8][64];

    const float* qkvb = qkv + (size_t)b*NTOK*2304;

    // load 8 q vectors
    for (int i = tid; i < 512; i += 256) {
        int qi = i >> 6, d = i & 63;
        qv[qi][d] = qkvb[(size_t)(n0+qi)*2304 + head*64 + d];
    }
    __syncthreads();

    // rel_h[qi][kh] = q_i . rel_pos_h[qh-kh+31];  rel_w[qi][kw] = q_i . rel_pos_w[qw-kw+31]
    for (int i = tid; i < 512; i += 256) {
        int qi = i >> 6, j = i & 63;
        if (j < 32) {
            const float* r = rph + (size_t)(qh - j + 31)*64;
            float a = 0.f;
            for (int d = 0; d < 64; ++d) a += qv[qi][d]*r[d];
            relh[qi][j] = a;
        } else {
            int kw = j - 32;
            const float* r = rpw + (size_t)(qw0 + qi - kw + 31)*64;
            float a = 0.f;
            for (int d = 0; d < 64; ++d) a += qv[qi][d]*r[d];
            relw[qi][kw] = a;
        }
    }
    __syncthreads();

    // scores: sc[qi][kk] = 0.125*q.k + relh + relw
    const float scale = 0.125f;
    for (int kk = tid; kk < 1024; kk += 256) {
        const float* kr = qkvb + (size_t)kk*2304 + 768 + head*64;
        float s[8];
        #pragma unroll
        for (int i = 0; i < 8; ++i) s[i] = 0.f;
        for (int d = 0; d < 64; ++d) {
            float kd = kr[d];
            #pragma unroll
            for (int i = 0; i < 8; ++i) s[i] += qv[i][d]*kd;
        }
        int kh = kk >> 5, kw = kk & 31;
        #pragma unroll
        for (int i = 0; i < 8; ++i)
            sc[i][kk] = s[i]*scale + relh[i][kh] + relw[i][kw];
    }
    __syncthreads();

    // softmax per query (fp32, max-shifted)
    for (int qi = 0; qi < 8; ++qi) {
        float m = -1e30f;
        for (int kk = tid; kk < 1024; kk += 256) m = fmaxf(m, sc[qi][kk]);
        red[tid] = m; __syncthreads();
        for (int o = 128; o > 0; o >>= 1) {
            if (tid < o) red[tid] = fmaxf(red[tid], red[tid+o]);
            __syncthreads();
        }
        m = red[0]; __syncthreads();
        float s = 0.f;
        for (int kk = tid; kk < 1024; kk += 256) {
            float e = __expf(sc[qi][kk]-m);
            sc[qi][kk] = e; s += e;
        }
        red[tid] = s; __syncthreads();
        for (int o = 128; o > 0; o >>= 1) {
            if (tid < o) red[tid] += red[tid+o];
            __syncthreads();
        }
        float invs = 1.f/red[0]; __syncthreads();
        for (int kk = tid; kk < 1024; kk += 256) sc[qi][kk] *= invs;
        __syncthreads();
    }

    // out = P @ V : thread handles dim d = tid&63 over key-chunk tid>>6
    int d = tid & 63, chunk = tid >> 6;
    float acc[8];
    #pragma unroll
    for (int i = 0; i < 8; ++i) acc[i] = 0.f;
    for (int kk = chunk*256; kk < chunk*256 + 256; ++kk) {
        float vv = qkvb[(size_t)kk*2304 + 1536 + head*64 + d];
        #pragma unroll
        for (int i = 0; i < 8; ++i) acc[i] += sc[i][kk]*vv;
    }
    #pragma unroll
    for (int i = 0; i < 8; ++i) part[chunk][i][d] = acc[i];
    __syncthreads();
    if (chunk == 0) {
        for (int i = 0; i < 8; ++i) {
            float o = part[0][i][d] + part[1][i][d] + part[2][i][d] + part[3][i][d];
            out[(size_t)(b*NTOK + n0 + i)*768 + head*64 + d] = o;
        }
    }
}

// ---------------- fp32 -> fp32 output copy -----------------------------------------
__global__ __launch_bounds__(256)
void copy_out(const float* __restrict__ in, float* __restrict__ out, int n)
{
    int i = blockIdx.x*256 + threadIdx.x;
    if (i < n) out[i] = in[i];
}

extern "C" void kernel_launch(void* const* d_in, const int* in_sizes, int n_in,
                              void* d_out, int out_size, void* d_ws, size_t ws_size,
                              hipStream_t stream)
{
    const float* x      = (const float*)d_in[0];
    const float* conv_w = (const float*)d_in[1];
    const float* conv_b = (const float*)d_in[2];
    const float* pos    = (const float*)d_in[3];
    const float* ln1_w  = (const float*)d_in[4];
    const float* ln1_b  = (const float*)d_in[5];
    const float* qkv_w  = (const float*)d_in[6];
    const float* qkv_b  = (const float*)d_in[7];
    const float* proj_w = (const float*)d_in[8];
    const float* proj_b = (const float*)d_in[9];
    const float* rph    = (const float*)d_in[10];
    const float* rpw    = (const float*)d_in[11];
    const float* ln2_w  = (const float*)d_in[12];
    const float* ln2_b  = (const float*)d_in[13];
    const float* fc1_w  = (const float*)d_in[14];
    const float* fc1_b  = (const float*)d_in[15];
    const float* fc2_w  = (const float*)d_in[16];
    const float* fc2_b  = (const float*)d_in[17];

    // workspace layout (fp32): h | x_ln | attn_out | big (qkv OR mlp, never both live)
    float* h      = (float*)d_ws;
    float* x_ln   = h      + (size_t)M_ROWS*EMBED;
    float* attn_o = x_ln   + (size_t)M_ROWS*EMBED;
    float* big    = attn_o + (size_t)M_ROWS*EMBED;   // 4096*3072 fp32

    dim3 blk16(16,16);

    patch_embed<<<M_ROWS, 256, 0, stream>>>(x, conv_w, conv_b, pos, h);

    for (int L = 0; L < 4; ++L) {
        layernorm<<<M_ROWS, 256, 0, stream>>>(h, ln1_w + L*EMBED, ln1_b + L*EMBED, x_ln);

        gemm_tiled<<<dim3(3*EMBED/16, M_ROWS/16), blk16, 0, stream>>>(
            x_ln, qkv_w + (size_t)L*EMBED*3*EMBED, qkv_b + (size_t)L*3*EMBED,
            nullptr, big, M_ROWS, 3*EMBED, EMBED, 0);

        attention<<<48*128, 256, 0, stream>>>(
            big, rph + (size_t)L*63*64, rpw + (size_t)L*63*64, attn_o);

        gemm_tiled<<<dim3(EMBED/16, M_ROWS/16), blk16, 0, stream>>>(
            attn_o, proj_w + (size_t)L*EMBED*EMBED, proj_b + (size_t)L*EMBED,
            h, h, M_ROWS, EMBED, EMBED, 0);

        layernorm<<<M_ROWS, 256, 0, stream>>>(h, ln2_w + L*EMBED, ln2_b + L*EMBED, x_ln);

        gemm_tiled<<<dim3(MLPD/16, M_ROWS/16), blk16, 0, stream>>>(
            x_ln, fc1_w + (size_t)L*EMBED*MLPD, fc1_b + (size_t)L*MLPD,
            nullptr, big, M_ROWS, MLPD, EMBED, 1);

        gemm_tiled<<<dim3(EMBED/16, M_ROWS/16), blk16, 0, stream>>>(
            big, fc2_w + (size_t)L*MLPD*EMBED, fc2_b + (size_t)L*EMBED,
            h, h, M_ROWS, EMBED, MLPD, 0);
    }

    copy_out<<<(M_ROWS*EMBED + 255)/256, 256, 0, stream>>>(
        h, (float*)d_out, M_ROWS*EMBED);
}

// Round 3
// 4290.115 us; speedup vs baseline: 4.0391x; 4.0391x over previous
//
#include <hip/hip_runtime.h>
#include <hip/hip_bf16.h>
#include <math.h>
#include <stdint.h>

#define EMBED 768
#define NTOK  1024   // 32*32
#define BATCH 4
#define NHEAD 12
#define HD    64
#define MLPD  3072
#define M_ROWS 4096  // BATCH*NTOK

typedef __attribute__((ext_vector_type(8))) short short8;   // 8 x bf16 (4 VGPRs)
typedef __attribute__((ext_vector_type(4))) float floatx4;

__device__ __forceinline__ float b2f(__hip_bfloat16 v) { return __bfloat162float(v); }

// async global->LDS, 16B per lane. lds base must be wave-uniform; HW adds lane*16.
__device__ __forceinline__ void gld_lds16(const void* g, void* l) {
    __builtin_amdgcn_global_load_lds(
        (const __attribute__((address_space(1))) uint32_t*)g,
        (__attribute__((address_space(3))) uint32_t*)l, 16, 0, 0);
}

// ---------------- patch embed: conv16x16 stride16 + bias + pos_embed -> h (fp32) ----
__global__ __launch_bounds__(256)
void patch_embed(const float* __restrict__ x,     // (4,3,512,512)
                 const float* __restrict__ w,     // (768,3,16,16)
                 const float* __restrict__ bias,  // (768)
                 const float* __restrict__ pos,   // (1,32,32,768)
                 float* __restrict__ h)           // (4096,768)
{
    int p  = blockIdx.x;
    int b  = p >> 10;
    int n  = p & 1023;
    int gh = n >> 5, gw = n & 31;
    int tid = threadIdx.x;

    __shared__ float patch[768];
    for (int i = tid; i < 768; i += 256) {
        int ci = i >> 8, r = i & 255, kh = r >> 4, kw = r & 15;
        patch[i] = x[(((size_t)b*3 + ci)*512 + (gh*16 + kh))*512 + gw*16 + kw];
    }
    __syncthreads();

    for (int c = tid; c < 768; c += 256) {
        const float* wr = w + (size_t)c*768;
        float acc = 0.f;
        for (int k = 0; k < 768; ++k) acc += patch[k] * wr[k];
        acc += bias[c] + pos[(size_t)n*768 + c];
        h[(size_t)p*768 + c] = acc;
    }
}

// ---------------- layernorm: fp32 in -> bf16 out ------------------------------------
__global__ __launch_bounds__(256)
void layernorm_bf16(const float* __restrict__ in,
                    const float* __restrict__ w,
                    const float* __restrict__ b,
                    __hip_bfloat16* __restrict__ out)
{
    int row = blockIdx.x;
    const float* xr = in + (size_t)row*768;
    int tid = threadIdx.x;
    float s = 0.f, ss = 0.f;
    for (int i = tid; i < 768; i += 256) { float v = xr[i]; s += v; ss += v*v; }
    __shared__ float rs[256], rss[256];
    rs[tid] = s; rss[tid] = ss; __syncthreads();
    for (int o = 128; o > 0; o >>= 1) {
        if (tid < o) { rs[tid] += rs[tid+o]; rss[tid] += rss[tid+o]; }
        __syncthreads();
    }
    float mean = rs[0] * (1.f/768.f);
    float var  = rss[0] * (1.f/768.f) - mean*mean;
    float inv  = rsqrtf(var + 1e-5f);
    for (int i = tid; i < 768; i += 256)
        out[(size_t)row*768 + i] = __float2bfloat16((xr[i]-mean)*inv*w[i] + b[i]);
}

// ---------------- weight transpose+convert: fp32 W[K][N] -> bf16 Wt[N][K] ----------
__global__ __launch_bounds__(256)
void transpose_cvt(const float* __restrict__ src, __hip_bfloat16* __restrict__ dst,
                   int K, int N)
{
    __shared__ float t[32][33];
    int n0 = blockIdx.x*32, k0 = blockIdx.y*32;
    int tx = threadIdx.x, ty = threadIdx.y;   // (32, 8)
    #pragma unroll
    for (int r = 0; r < 4; ++r) {
        int row = ty + r*8;
        t[row][tx] = src[(size_t)(k0+row)*N + n0 + tx];
    }
    __syncthreads();
    #pragma unroll
    for (int r = 0; r < 4; ++r) {
        int row = ty + r*8;
        dst[(size_t)(n0+row)*K + k0 + tx] = __float2bfloat16(t[tx][row]);
    }
}

// ---------------- MFMA GEMM: C[M,N] = epi(A[M,K] @ Bt[N,K]^T + bias) ----------------
// A,Bt bf16; acc fp32. 128x128 tile, BK=32, 256 thr = 4 waves (2x2), 4x4 MFMA/wave.
__global__ __launch_bounds__(256)
void gemm_mfma(const __hip_bfloat16* __restrict__ A,
               const __hip_bfloat16* __restrict__ Bt,
               const float* __restrict__ bias,
               const float* __restrict__ res,     // fp32 or null
               float* __restrict__ Cf,            // fp32 out (or null)
               __hip_bfloat16* __restrict__ Cb,   // bf16 out (or null)
               int M, int N, int K, int dogelu)
{
    __shared__ __hip_bfloat16 As[128*32];
    __shared__ __hip_bfloat16 Bs[128*32];

    const int tid  = threadIdx.x;
    const int lane = tid & 63;
    const int wid  = tid >> 6;          // 0..3
    const int wr   = wid >> 1;          // wave row (2x2)
    const int wc   = wid & 1;           // wave col
    const int lr   = lane & 15;
    const int quad = lane >> 4;

    const int bm = blockIdx.y * 128;
    const int bn = blockIdx.x * 128;

    // staging decomposition: call c (0,1): row = c*64 + tid/4, kchunk = tid&3
    const int srow   = tid >> 2;
    const int skoff  = (tid & 3) * 8;
    // wave-uniform LDS base for this thread's wave: wid*64 lanes * 16B
    const int wbase  = wid * 1024;      // bytes

    floatx4 acc[4][4];
    #pragma unroll
    for (int i = 0; i < 4; ++i)
        #pragma unroll
        for (int j = 0; j < 4; ++j)
            acc[i][j] = (floatx4){0.f,0.f,0.f,0.f};

    for (int k0 = 0; k0 < K; k0 += 32) {
        #pragma unroll
        for (int c = 0; c < 2; ++c) {
            gld_lds16(A  + (size_t)(bm + c*64 + srow)*K + k0 + skoff,
                      (char*)As + c*4096 + wbase);
            gld_lds16(Bt + (size_t)(bn + c*64 + srow)*K + k0 + skoff,
                      (char*)Bs + c*4096 + wbase);
        }
        __syncthreads();

        short8 a[4], b[4];
        #pragma unroll
        for (int i = 0; i < 4; ++i)
            a[i] = *(const short8*)((const void*)(As + (wr*64 + i*16 + lr)*32 + quad*8));
        #pragma unroll
        for (int j = 0; j < 4; ++j)
            b[j] = *(const short8*)((const void*)(Bs + (wc*64 + j*16 + lr)*32 + quad*8));
        #pragma unroll
        for (int i = 0; i < 4; ++i)
            #pragma unroll
            for (int j = 0; j < 4; ++j)
                acc[i][j] = __builtin_amdgcn_mfma_f32_16x16x32_bf16(a[i], b[j], acc[i][j], 0, 0, 0);
        __syncthreads();
    }

    // epilogue: C/D layout col=lane&15, row=quad*4+reg
    #pragma unroll
    for (int j = 0; j < 4; ++j) {
        int col = bn + wc*64 + j*16 + lr;
        float bs = bias[col];
        #pragma unroll
        for (int i = 0; i < 4; ++i) {
            #pragma unroll
            for (int r = 0; r < 4; ++r) {
                int row = bm + wr*64 + i*16 + quad*4 + r;
                float val = acc[i][j][r] + bs;
                if (dogelu) val = 0.5f*val*(1.f + erff(val*0.70710678118f));
                if (res) val += res[(size_t)row*N + col];
                if (Cf) Cf[(size_t)row*N + col] = val;
                else    Cb[(size_t)row*N + col] = __float2bfloat16(val);
            }
        }
    }
}

// ---------------- fused attention with decomposed rel-pos ---------------------------
// One block: 8 consecutive queries (same qh row) for one (b,head). out bf16.
__global__ __launch_bounds__(256)
void attention(const float* __restrict__ qkv,     // (4,1024,2304) fp32
               const float* __restrict__ rph,     // (63,64) this layer
               const float* __restrict__ rpw,     // (63,64)
               __hip_bfloat16* __restrict__ out)  // (4,1024,768) bf16
{
    int bh   = blockIdx.x >> 7;
    int qblk = blockIdx.x & 127;
    int b    = bh / NHEAD;
    int head = bh % NHEAD;
    int n0   = qblk * 8;
    int qh   = n0 >> 5;
    int qw0  = n0 & 31;
    int tid  = threadIdx.x;

    __shared__ float qv[8][64];
    __shared__ float relh[8][32];
    __shared__ float relw[8][32];
    __shared__ float sc[8][1024];
    __shared__ float red[256];
    __shared__ float part[4][8][64];

    const float* qkvb = qkv + (size_t)b*NTOK*2304;

    for (int i = tid; i < 512; i += 256) {
        int qi = i >> 6, d = i & 63;
        qv[qi][d] = qkvb[(size_t)(n0+qi)*2304 + head*64 + d];
    }
    __syncthreads();

    for (int i = tid; i < 512; i += 256) {
        int qi = i >> 6, j = i & 63;
        if (j < 32) {
            const float* r = rph + (size_t)(qh - j + 31)*64;
            float a = 0.f;
            for (int d = 0; d < 64; ++d) a += qv[qi][d]*r[d];
            relh[qi][j] = a;
        } else {
            int kw = j - 32;
            const float* r = rpw + (size_t)(qw0 + qi - kw + 31)*64;
            float a = 0.f;
            for (int d = 0; d < 64; ++d) a += qv[qi][d]*r[d];
            relw[qi][kw] = a;
        }
    }
    __syncthreads();

    const float scale = 0.125f;
    for (int kk = tid; kk < 1024; kk += 256) {
        const float* kr = qkvb + (size_t)kk*2304 + 768 + head*64;
        float s[8];
        #pragma unroll
        for (int i = 0; i < 8; ++i) s[i] = 0.f;
        for (int d = 0; d < 64; ++d) {
            float kd = kr[d];
            #pragma unroll
            for (int i = 0; i < 8; ++i) s[i] += qv[i][d]*kd;
        }
        int kh = kk >> 5, kw = kk & 31;
        #pragma unroll
        for (int i = 0; i < 8; ++i)
            sc[i][kk] = s[i]*scale + relh[i][kh] + relw[i][kw];
    }
    __syncthreads();

    for (int qi = 0; qi < 8; ++qi) {
        float m = -1e30f;
        for (int kk = tid; kk < 1024; kk += 256) m = fmaxf(m, sc[qi][kk]);
        red[tid] = m; __syncthreads();
        for (int o = 128; o > 0; o >>= 1) {
            if (tid < o) red[tid] = fmaxf(red[tid], red[tid+o]);
            __syncthreads();
        }
        m = red[0]; __syncthreads();
        float s = 0.f;
        for (int kk = tid; kk < 1024; kk += 256) {
            float e = __expf(sc[qi][kk]-m);
            sc[qi][kk] = e; s += e;
        }
        red[tid] = s; __syncthreads();
        for (int o = 128; o > 0; o >>= 1) {
            if (tid < o) red[tid] += red[tid+o];
            __syncthreads();
        }
        float invs = 1.f/red[0]; __syncthreads();
        for (int kk = tid; kk < 1024; kk += 256) sc[qi][kk] *= invs;
        __syncthreads();
    }

    int d = tid & 63, chunk = tid >> 6;
    float acc[8];
    #pragma unroll
    for (int i = 0; i < 8; ++i) acc[i] = 0.f;
    for (int kk = chunk*256; kk < chunk*256 + 256; ++kk) {
        float vv = qkvb[(size_t)kk*2304 + 1536 + head*64 + d];
        #pragma unroll
        for (int i = 0; i < 8; ++i) acc[i] += sc[i][kk]*vv;
    }
    #pragma unroll
    for (int i = 0; i < 8; ++i) part[chunk][i][d] = acc[i];
    __syncthreads();
    if (chunk == 0) {
        for (int i = 0; i < 8; ++i) {
            float o = part[0][i][d] + part[1][i][d] + part[2][i][d] + part[3][i][d];
            out[(size_t)(b*NTOK + n0 + i)*768 + head*64 + d] = __float2bfloat16(o);
        }
    }
}

// ---------------- output copy -------------------------------------------------------
__global__ __launch_bounds__(256)
void copy_out(const float* __restrict__ in, float* __restrict__ out, int n)
{
    int i = blockIdx.x*256 + threadIdx.x;
    if (i < n) out[i] = in[i];
}

extern "C" void kernel_launch(void* const* d_in, const int* in_sizes, int n_in,
                              void* d_out, int out_size, void* d_ws, size_t ws_size,
                              hipStream_t stream)
{
    const float* x      = (const float*)d_in[0];
    const float* conv_w = (const float*)d_in[1];
    const float* conv_b = (const float*)d_in[2];
    const float* pos    = (const float*)d_in[3];
    const float* ln1_w  = (const float*)d_in[4];
    const float* ln1_b  = (const float*)d_in[5];
    const float* qkv_w  = (const float*)d_in[6];
    const float* qkv_b  = (const float*)d_in[7];
    const float* proj_w = (const float*)d_in[8];
    const float* proj_b = (const float*)d_in[9];
    const float* rph    = (const float*)d_in[10];
    const float* rpw    = (const float*)d_in[11];
    const float* ln2_w  = (const float*)d_in[12];
    const float* ln2_b  = (const float*)d_in[13];
    const float* fc1_w  = (const float*)d_in[14];
    const float* fc1_b  = (const float*)d_in[15];
    const float* fc2_w  = (const float*)d_in[16];
    const float* fc2_b  = (const float*)d_in[17];

    // ws layout:
    //   h      fp32 4096x768                    (12.6 MB)
    //   qkv    fp32 4096x2304  UNION mlp bf16 4096x3072   (37.7 MB)
    //   x_ln   bf16 4096x768                    (6.3 MB)
    //   attn_o bf16 4096x768                    (6.3 MB)
    //   wbuf   bf16 per-layer transposed weights (14.2 MB)
    char* p = (char*)d_ws;
    float*           h      = (float*)p;             p += (size_t)M_ROWS*EMBED*4;
    float*           qkv    = (float*)p;
    __hip_bfloat16*  mlp    = (__hip_bfloat16*)p;    p += (size_t)M_ROWS*3*EMBED*4;
    __hip_bfloat16*  x_ln   = (__hip_bfloat16*)p;    p += (size_t)M_ROWS*EMBED*2;
    __hip_bfloat16*  attn_o = (__hip_bfloat16*)p;    p += (size_t)M_ROWS*EMBED*2;
    __hip_bfloat16*  qkv_wt = (__hip_bfloat16*)p;    p += (size_t)2304*768*2;
    __hip_bfloat16*  proj_wt= (__hip_bfloat16*)p;    p += (size_t)768*768*2;
    __hip_bfloat16*  fc1_wt = (__hip_bfloat16*)p;    p += (size_t)MLPD*768*2;
    __hip_bfloat16*  fc2_wt = (__hip_bfloat16*)p;    p += (size_t)768*MLPD*2;

    dim3 tblk(32, 8);

    patch_embed<<<M_ROWS, 256, 0, stream>>>(x, conv_w, conv_b, pos, h);

    for (int L = 0; L < 4; ++L) {
        // convert this layer's weights: W[K][N] -> bf16 Wt[N][K]
        transpose_cvt<<<dim3(2304/32, 768/32), tblk, 0, stream>>>(
            qkv_w + (size_t)L*768*2304, qkv_wt, 768, 2304);
        transpose_cvt<<<dim3(768/32, 768/32), tblk, 0, stream>>>(
            proj_w + (size_t)L*768*768, proj_wt, 768, 768);
        transpose_cvt<<<dim3(MLPD/32, 768/32), tblk, 0, stream>>>(
            fc1_w + (size_t)L*768*MLPD, fc1_wt, 768, MLPD);
        transpose_cvt<<<dim3(768/32, MLPD/32), tblk, 0, stream>>>(
            fc2_w + (size_t)L*MLPD*768, fc2_wt, MLPD, 768);

        layernorm_bf16<<<M_ROWS, 256, 0, stream>>>(h, ln1_w + L*EMBED, ln1_b + L*EMBED, x_ln);

        gemm_mfma<<<dim3(2304/128, M_ROWS/128), 256, 0, stream>>>(
            x_ln, qkv_wt, qkv_b + (size_t)L*3*EMBED, nullptr,
            qkv, nullptr, M_ROWS, 2304, 768, 0);

        attention<<<48*128, 256, 0, stream>>>(
            qkv, rph + (size_t)L*63*64, rpw + (size_t)L*63*64, attn_o);

        gemm_mfma<<<dim3(768/128, M_ROWS/128), 256, 0, stream>>>(
            attn_o, proj_wt, proj_b + (size_t)L*EMBED, h,
            h, nullptr, M_ROWS, 768, 768, 0);

        layernorm_bf16<<<M_ROWS, 256, 0, stream>>>(h, ln2_w + L*EMBED, ln2_b + L*EMBED, x_ln);

        gemm_mfma<<<dim3(MLPD/128, M_ROWS/128), 256, 0, stream>>>(
            x_ln, fc1_wt, fc1_b + (size_t)L*MLPD, nullptr,
            nullptr, mlp, M_ROWS, MLPD, 768, 1);

        gemm_mfma<<<dim3(768/128, M_ROWS/128), 256, 0, stream>>>(
            mlp, fc2_wt, fc2_b + (size_t)L*EMBED, h,
            h, nullptr, M_ROWS, 768, MLPD, 0);
    }

    copy_out<<<(M_ROWS*EMBED + 255)/256, 256, 0, stream>>>(
        h, (float*)d_out, M_ROWS*EMBED);
}

// Round 4
// 1619.325 us; speedup vs baseline: 10.7009x; 2.6493x over previous
//
#include <hip/hip_runtime.h>
#include <hip/hip_bf16.h>
#include <math.h>
#include <stdint.h>

#define EMBED 768
#define NTOK  1024   // 32*32
#define BATCH 4
#define NHEAD 12
#define HD    64
#define MLPD  3072
#define M_ROWS 4096  // BATCH*NTOK

typedef __attribute__((ext_vector_type(8))) short short8;   // 8 x bf16 (4 VGPRs)
typedef __attribute__((ext_vector_type(4))) float floatx4;

__device__ __forceinline__ float b2f(__hip_bfloat16 v) { return __bfloat162float(v); }

// async global->LDS, 16B per lane. LDS base must be wave-uniform; HW adds lane*16.
__device__ __forceinline__ void gld_lds16(const void* g, void* l) {
    __builtin_amdgcn_global_load_lds(
        (const __attribute__((address_space(1))) uint32_t*)g,
        (__attribute__((address_space(3))) uint32_t*)l, 16, 0, 0);
}

// ---------------- im2col: x (4,3,512,512) fp32 -> A_im (4096,768) bf16 --------------
__global__ __launch_bounds__(256)
void im2col(const float* __restrict__ x, __hip_bfloat16* __restrict__ A)
{
    int p  = blockIdx.x;
    int b  = p >> 10;
    int n  = p & 1023;
    int gh = n >> 5, gw = n & 31;
    int tid = threadIdx.x;
    for (int i = tid; i < 768; i += 256) {
        int ci = i >> 8, r = i & 255, kh = r >> 4, kw = r & 15;
        A[(size_t)p*768 + i] = __float2bfloat16(
            x[(((size_t)b*3 + ci)*512 + (gh*16 + kh))*512 + gw*16 + kw]);
    }
}

// ---------------- elementwise fp32 -> bf16 cast -------------------------------------
__global__ __launch_bounds__(256)
void cvt_bf16(const float* __restrict__ in, __hip_bfloat16* __restrict__ out, int n)
{
    int i = blockIdx.x*256 + threadIdx.x;
    if (i < n) out[i] = __float2bfloat16(in[i]);
}

// ---------------- layernorm: fp32 in -> bf16 out ------------------------------------
__global__ __launch_bounds__(256)
void layernorm_bf16(const float* __restrict__ in,
                    const float* __restrict__ w,
                    const float* __restrict__ b,
                    __hip_bfloat16* __restrict__ out)
{
    int row = blockIdx.x;
    const float* xr = in + (size_t)row*768;
    int tid = threadIdx.x;
    float s = 0.f, ss = 0.f;
    for (int i = tid; i < 768; i += 256) { float v = xr[i]; s += v; ss += v*v; }
    __shared__ float rs[256], rss[256];
    rs[tid] = s; rss[tid] = ss; __syncthreads();
    for (int o = 128; o > 0; o >>= 1) {
        if (tid < o) { rs[tid] += rs[tid+o]; rss[tid] += rss[tid+o]; }
        __syncthreads();
    }
    float mean = rs[0] * (1.f/768.f);
    float var  = rss[0] * (1.f/768.f) - mean*mean;
    float inv  = rsqrtf(var + 1e-5f);
    for (int i = tid; i < 768; i += 256)
        out[(size_t)row*768 + i] = __float2bfloat16((xr[i]-mean)*inv*w[i] + b[i]);
}

// ---------------- weight transpose+convert: fp32 W[K][N] -> bf16 Wt[N][K] ----------
__global__ __launch_bounds__(256)
void transpose_cvt(const float* __restrict__ src, __hip_bfloat16* __restrict__ dst,
                   int K, int N)
{
    __shared__ float t[32][33];
    int n0 = blockIdx.x*32, k0 = blockIdx.y*32;
    int tx = threadIdx.x, ty = threadIdx.y;   // (32, 8)
    #pragma unroll
    for (int r = 0; r < 4; ++r) {
        int row = ty + r*8;
        t[row][tx] = src[(size_t)(k0+row)*N + n0 + tx];
    }
    __syncthreads();
    #pragma unroll
    for (int r = 0; r < 4; ++r) {
        int row = ty + r*8;
        dst[(size_t)(n0+row)*K + k0 + tx] = __float2bfloat16(t[tx][row]);
    }
}

// ---------------- MFMA GEMM: C[M,N] = epi(A[M,K] @ Bt[N,K]^T + bias) ----------------
// emode 0: fp32 out Cf (+res, +posadd, gelu) ; emode 1: bf16 out Cb (gelu) ;
// emode 2: qkv permute -> qp/kp [bh][n][64] bf16, vp [bh][64][n] bf16.
__global__ __launch_bounds__(256)
void gemm_mfma(const __hip_bfloat16* __restrict__ A,
               const __hip_bfloat16* __restrict__ Bt,
               const float* __restrict__ bias,
               const float* __restrict__ res,
               const float* __restrict__ posadd,
               float* __restrict__ Cf,
               __hip_bfloat16* __restrict__ Cb,
               __hip_bfloat16* __restrict__ qp,
               __hip_bfloat16* __restrict__ kp,
               __hip_bfloat16* __restrict__ vp,
               int M, int N, int K, int dogelu, int emode)
{
    __shared__ __align__(16) __hip_bfloat16 As[128*32];
    __shared__ __align__(16) __hip_bfloat16 Bs[128*32];

    const int tid  = threadIdx.x;
    const int lane = tid & 63;
    const int wid  = tid >> 6;
    const int wr   = wid >> 1;
    const int wc   = wid & 1;
    const int lr   = lane & 15;
    const int quad = lane >> 4;

    const int bm = blockIdx.y * 128;
    const int bn = blockIdx.x * 128;

    const int srow  = tid >> 2;
    const int skoff = (tid & 3) * 8;
    const int wbase = wid * 1024;      // bytes

    floatx4 acc[4][4];
    #pragma unroll
    for (int i = 0; i < 4; ++i)
        #pragma unroll
        for (int j = 0; j < 4; ++j)
            acc[i][j] = (floatx4){0.f,0.f,0.f,0.f};

    for (int k0 = 0; k0 < K; k0 += 32) {
        #pragma unroll
        for (int c = 0; c < 2; ++c) {
            gld_lds16(A  + (size_t)(bm + c*64 + srow)*K + k0 + skoff,
                      (char*)As + c*4096 + wbase);
            gld_lds16(Bt + (size_t)(bn + c*64 + srow)*K + k0 + skoff,
                      (char*)Bs + c*4096 + wbase);
        }
        __syncthreads();

        short8 a[4], b[4];
        #pragma unroll
        for (int i = 0; i < 4; ++i)
            a[i] = *(const short8*)((const void*)(As + (wr*64 + i*16 + lr)*32 + quad*8));
        #pragma unroll
        for (int j = 0; j < 4; ++j)
            b[j] = *(const short8*)((const void*)(Bs + (wc*64 + j*16 + lr)*32 + quad*8));
        #pragma unroll
        for (int i = 0; i < 4; ++i)
            #pragma unroll
            for (int j = 0; j < 4; ++j)
                acc[i][j] = __builtin_amdgcn_mfma_f32_16x16x32_bf16(a[i], b[j], acc[i][j], 0, 0, 0);
        __syncthreads();
    }

    // epilogue: C/D layout col=lane&15, row=quad*4+reg
    #pragma unroll
    for (int j = 0; j < 4; ++j) {
        int col = bn + wc*64 + j*16 + lr;
        float bs = bias[col];
        #pragma unroll
        for (int i = 0; i < 4; ++i) {
            #pragma unroll
            for (int r = 0; r < 4; ++r) {
                int row = bm + wr*64 + i*16 + quad*4 + r;
                float val = acc[i][j][r] + bs;
                if (emode == 2) {
                    int which = col / 768;
                    int hd    = col % 768;
                    int head  = hd >> 6;
                    int d     = hd & 63;
                    int b_    = row >> 10;
                    int n_    = row & 1023;
                    int bh    = b_*NHEAD + head;
                    __hip_bfloat16 bv = __float2bfloat16(val);
                    if      (which == 0) qp[((size_t)bh*NTOK + n_)*HD + d] = bv;
                    else if (which == 1) kp[((size_t)bh*NTOK + n_)*HD + d] = bv;
                    else                 vp[((size_t)bh*HD + d)*NTOK + n_] = bv;
                } else {
                    if (dogelu) val = 0.5f*val*(1.f + erff(val*0.70710678118f));
                    if (res)    val += res[(size_t)row*N + col];
                    if (posadd) val += posadd[(size_t)(row & 1023)*N + col];
                    if (emode == 0) Cf[(size_t)row*N + col] = val;
                    else            Cb[(size_t)row*N + col] = __float2bfloat16(val);
                }
            }
        }
    }
}

// ---------------- MFMA flash attention with decomposed rel-pos ----------------------
// grid = 48 (b,h) * 16 q-tiles. Block: 4 waves, wave w owns queries [w*16, w*16+16).
__global__ __launch_bounds__(256)
void attention_mfma(const __hip_bfloat16* __restrict__ qp,   // [48][1024][64]
                    const __hip_bfloat16* __restrict__ kp,   // [48][1024][64]
                    const __hip_bfloat16* __restrict__ vp,   // [48][64][1024] (V^T)
                    const float* __restrict__ rph,           // (63,64) this layer
                    const float* __restrict__ rpw,           // (63,64)
                    __hip_bfloat16* __restrict__ out)        // (4,1024,768) bf16
{
    const int blk  = blockIdx.x;
    const int bh   = blk >> 4;
    const int qt   = blk & 15;
    const int b    = bh / NHEAD;
    const int head = bh % NHEAD;
    const int tid  = threadIdx.x;
    const int lane = tid & 63;
    const int w    = tid >> 6;
    const int lr   = lane & 15;
    const int quad = lane >> 4;

    __shared__ __align__(16) __hip_bfloat16 Qs[64*64];      // [qlocal][d]
    __shared__ __align__(16) __hip_bfloat16 Ks[64*64];      // [klocal][d]
    __shared__ __align__(16) __hip_bfloat16 Vs[64*64];      // [d][klocal]  (V^T tile)
    __shared__ __align__(16) __hip_bfloat16 Ps[4*16*64];    // per-wave P; aliased as G in prologue
    __shared__ __align__(16) float relhS[64*32];            // [qlocal][kh]
    __shared__ __align__(16) float relwS[64*32];            // [qlocal][kw]

    const __hip_bfloat16* qbase  = qp + ((size_t)bh*NTOK + qt*64)*HD;
    const __hip_bfloat16* kbase  = kp + (size_t)bh*NTOK*HD;
    const __hip_bfloat16* vtbase = vp + (size_t)bh*HD*NTOK;

    // ---- stage Q tile (contiguous 8 KB) ----
    #pragma unroll
    for (int c = 0; c < 2; ++c)
        gld_lds16(qbase + (size_t)(c*256 + tid)*8, (char*)Qs + c*4096 + w*1024);
    __syncthreads();

    // ---- prologue: relh via MFMA (G gathered into Ps region), relw via VALU ----
    const int qh0 = qt*2;
    __hip_bfloat16* G = Ps;   // G[hh][kh][d] : 2*32*64 bf16 = 8 KB
    for (int i = tid; i < 4096; i += 256) {
        int hh = i >> 11, kh = (i >> 6) & 31, d = i & 63;
        G[i] = __float2bfloat16(rph[(size_t)(qh0 + hh - kh + 31)*HD + d]);
    }
    __syncthreads();

    short8 qa0 = *(const short8*)((const void*)(Qs + (w*16 + lr)*64 + quad*8));
    short8 qa1 = *(const short8*)((const void*)(Qs + (w*16 + lr)*64 + 32 + quad*8));

    {
        const __hip_bfloat16* Gh = G + (w >> 1)*2048;
        #pragma unroll
        for (int j = 0; j < 2; ++j) {
            short8 b0 = *(const short8*)((const void*)(Gh + (j*16 + lr)*64 + quad*8));
            short8 b1 = *(const short8*)((const void*)(Gh + (j*16 + lr)*64 + 32 + quad*8));
            floatx4 rh = (floatx4){0.f,0.f,0.f,0.f};
            rh = __builtin_amdgcn_mfma_f32_16x16x32_bf16(qa0, b0, rh, 0, 0, 0);
            rh = __builtin_amdgcn_mfma_f32_16x16x32_bf16(qa1, b1, rh, 0, 0, 0);
            #pragma unroll
            for (int rr = 0; rr < 4; ++rr)
                relhS[(w*16 + quad*4 + rr)*32 + j*16 + lr] = rh[rr];
        }
    }

    // relw: q's table row depends on q itself -> VALU dots
    for (int i = tid; i < 2048; i += 256) {
        int q = i >> 5, kw = i & 31;
        const float* tw = rpw + (size_t)((q & 31) - kw + 31)*HD;
        const __hip_bfloat16* qq = Qs + q*64;
        float a = 0.f;
        #pragma unroll
        for (int d = 0; d < 64; ++d) a += b2f(qq[d]) * tw[d];
        relwS[i] = a;
    }
    __syncthreads();

    // per-lane rel-w registers (kw = (j&1)*16 + lr, constant across k-tiles)
    float rw[4][2];
    #pragma unroll
    for (int rr = 0; rr < 4; ++rr)
        #pragma unroll
        for (int jp = 0; jp < 2; ++jp)
            rw[rr][jp] = relwS[(w*16 + quad*4 + rr)*32 + jp*16 + lr];

    floatx4 o[4];
    #pragma unroll
    for (int ds = 0; ds < 4; ++ds) o[ds] = (floatx4){0.f,0.f,0.f,0.f};
    float m_run[4], l_run[4];
    #pragma unroll
    for (int rr = 0; rr < 4; ++rr) { m_run[rr] = -3.0e38f; l_run[rr] = 0.f; }

    const float scale = 0.125f;

    for (int kt = 0; kt < 16; ++kt) {
        // stage K tile (contiguous) and V^T tile (64 rows x 128B)
        const __hip_bfloat16* kb = kbase + (size_t)kt*64*HD;
        #pragma unroll
        for (int c = 0; c < 2; ++c) {
            gld_lds16(kb + (size_t)(c*256 + tid)*8, (char*)Ks + c*4096 + w*1024);
            int idx = c*256 + tid;
            int dd = idx >> 3, ch = idx & 7;
            gld_lds16(vtbase + (size_t)dd*NTOK + kt*64 + ch*8, (char*)Vs + c*4096 + w*1024);
        }
        __syncthreads();

        // S = scale * Q K^T + relh + relw
        floatx4 s[4];
        #pragma unroll
        for (int j = 0; j < 4; ++j) {
            short8 b0 = *(const short8*)((const void*)(Ks + (j*16 + lr)*64 + quad*8));
            short8 b1 = *(const short8*)((const void*)(Ks + (j*16 + lr)*64 + 32 + quad*8));
            floatx4 z = (floatx4){0.f,0.f,0.f,0.f};
            z = __builtin_amdgcn_mfma_f32_16x16x32_bf16(qa0, b0, z, 0, 0, 0);
            z = __builtin_amdgcn_mfma_f32_16x16x32_bf16(qa1, b1, z, 0, 0, 0);
            s[j] = z;
        }
        float2 rh2[4];
        #pragma unroll
        for (int rr = 0; rr < 4; ++rr)
            rh2[rr] = *(const float2*)((const void*)(relhS + (w*16 + quad*4 + rr)*32 + kt*2));
        #pragma unroll
        for (int j = 0; j < 4; ++j)
            #pragma unroll
            for (int rr = 0; rr < 4; ++rr)
                s[j][rr] = s[j][rr]*scale + ((j < 2) ? rh2[rr].x : rh2[rr].y) + rw[rr][j & 1];

        // online softmax per query row (row rr lives in 16 lanes sharing quad)
        float mloc[4];
        #pragma unroll
        for (int rr = 0; rr < 4; ++rr)
            mloc[rr] = fmaxf(fmaxf(s[0][rr], s[1][rr]), fmaxf(s[2][rr], s[3][rr]));
        #pragma unroll
        for (int off = 1; off < 16; off <<= 1)
            #pragma unroll
            for (int rr = 0; rr < 4; ++rr)
                mloc[rr] = fmaxf(mloc[rr], __shfl_xor(mloc[rr], off, 16));

        float p[4][4], lloc[4];
        #pragma unroll
        for (int rr = 0; rr < 4; ++rr) {
            float mn = fmaxf(m_run[rr], mloc[rr]);
            float al = __expf(m_run[rr] - mn);
            m_run[rr] = mn;
            l_run[rr] *= al;
            #pragma unroll
            for (int ds = 0; ds < 4; ++ds) o[ds][rr] *= al;
            float ls = 0.f;
            #pragma unroll
            for (int j = 0; j < 4; ++j) { p[j][rr] = __expf(s[j][rr] - mn); ls += p[j][rr]; }
            lloc[rr] = ls;
        }
        #pragma unroll
        for (int off = 1; off < 16; off <<= 1)
            #pragma unroll
            for (int rr = 0; rr < 4; ++rr)
                lloc[rr] += __shfl_xor(lloc[rr], off, 16);
        #pragma unroll
        for (int rr = 0; rr < 4; ++rr) l_run[rr] += lloc[rr];

        // P: C-layout -> LDS -> A-layout (per-wave region, intra-wave dependency)
        #pragma unroll
        for (int j = 0; j < 4; ++j)
            #pragma unroll
            for (int rr = 0; rr < 4; ++rr)
                Ps[w*1024 + (quad*4 + rr)*64 + j*16 + lr] = __float2bfloat16(p[j][rr]);

        short8 pa0 = *(const short8*)((const void*)(Ps + w*1024 + lr*64 + quad*8));
        short8 pa1 = *(const short8*)((const void*)(Ps + w*1024 + lr*64 + 32 + quad*8));
        #pragma unroll
        for (int ds = 0; ds < 4; ++ds) {
            short8 v0 = *(const short8*)((const void*)(Vs + (ds*16 + lr)*64 + quad*8));
            short8 v1 = *(const short8*)((const void*)(Vs + (ds*16 + lr)*64 + 32 + quad*8));
            o[ds] = __builtin_amdgcn_mfma_f32_16x16x32_bf16(pa0, v0, o[ds], 0, 0, 0);
            o[ds] = __builtin_amdgcn_mfma_f32_16x16x32_bf16(pa1, v1, o[ds], 0, 0, 0);
        }
        __syncthreads();
    }

    // epilogue: O /= l, write bf16 to (b, n, head*64 + d)
    #pragma unroll
    for (int rr = 0; rr < 4; ++rr) {
        float inv = 1.f / l_run[rr];
        int n = qt*64 + w*16 + quad*4 + rr;
        size_t base = ((size_t)b*NTOK + n)*EMBED + head*HD;
        #pragma unroll
        for (int ds = 0; ds < 4; ++ds)
            out[base + ds*16 + lr] = __float2bfloat16(o[ds][rr] * inv);
    }
}

// ---------------- output copy -------------------------------------------------------
__global__ __launch_bounds__(256)
void copy_out(const float* __restrict__ in, float* __restrict__ out, int n)
{
    int i = blockIdx.x*256 + threadIdx.x;
    if (i < n) out[i] = in[i];
}

extern "C" void kernel_launch(void* const* d_in, const int* in_sizes, int n_in,
                              void* d_out, int out_size, void* d_ws, size_t ws_size,
                              hipStream_t stream)
{
    const float* x      = (const float*)d_in[0];
    const float* conv_w = (const float*)d_in[1];
    const float* conv_b = (const float*)d_in[2];
    const float* pos    = (const float*)d_in[3];
    const float* ln1_w  = (const float*)d_in[4];
    const float* ln1_b  = (const float*)d_in[5];
    const float* qkv_w  = (const float*)d_in[6];
    const float* qkv_b  = (const float*)d_in[7];
    const float* proj_w = (const float*)d_in[8];
    const float* proj_b = (const float*)d_in[9];
    const float* rph    = (const float*)d_in[10];
    const float* rpw    = (const float*)d_in[11];
    const float* ln2_w  = (const float*)d_in[12];
    const float* ln2_b  = (const float*)d_in[13];
    const float* fc1_w  = (const float*)d_in[14];
    const float* fc1_b  = (const float*)d_in[15];
    const float* fc2_w  = (const float*)d_in[16];
    const float* fc2_b  = (const float*)d_in[17];

    // ws layout:
    //  h       fp32 [4096][768]            12.58 MB
    //  q_perm  bf16 [48][1024][64]          6.29 MB
    //  k_perm  bf16 [48][1024][64]          6.29 MB
    //  vt_perm bf16 [48][64][1024]          6.29 MB
    //  x_ln    bf16 [4096][768]             6.29 MB
    //  attn_o  bf16 [4096][768]             6.29 MB
    //  mlp     bf16 [4096][3072] (also A_im during patch embed)  25.17 MB
    //  qkv_wt  bf16 [2304][768]  (also conv_wt before layer 0)    3.54 MB
    //  proj_wt bf16 [768][768]              1.18 MB
    //  fc1_wt  bf16 [3072][768]             4.72 MB
    //  fc2_wt  bf16 [768][3072]             4.72 MB
    char* p = (char*)d_ws;
    float*           h       = (float*)p;           p += (size_t)M_ROWS*EMBED*4;
    __hip_bfloat16*  q_perm  = (__hip_bfloat16*)p;  p += (size_t)48*NTOK*HD*2;
    __hip_bfloat16*  k_perm  = (__hip_bfloat16*)p;  p += (size_t)48*NTOK*HD*2;
    __hip_bfloat16*  vt_perm = (__hip_bfloat16*)p;  p += (size_t)48*NTOK*HD*2;
    __hip_bfloat16*  x_ln    = (__hip_bfloat16*)p;  p += (size_t)M_ROWS*EMBED*2;
    __hip_bfloat16*  attn_o  = (__hip_bfloat16*)p;  p += (size_t)M_ROWS*EMBED*2;
    __hip_bfloat16*  mlp     = (__hip_bfloat16*)p;  p += (size_t)M_ROWS*MLPD*2;
    __hip_bfloat16*  qkv_wt  = (__hip_bfloat16*)p;  p += (size_t)2304*768*2;
    __hip_bfloat16*  proj_wt = (__hip_bfloat16*)p;  p += (size_t)768*768*2;
    __hip_bfloat16*  fc1_wt  = (__hip_bfloat16*)p;  p += (size_t)MLPD*768*2;
    __hip_bfloat16*  fc2_wt  = (__hip_bfloat16*)p;  p += (size_t)768*MLPD*2;

    __hip_bfloat16*  A_im    = mlp;      // alias: not simultaneously live
    __hip_bfloat16*  conv_wt = qkv_wt;   // alias: overwritten at layer 0

    dim3 tblk(32, 8);

    // ---- patch embed as GEMM ----
    im2col<<<M_ROWS, 256, 0, stream>>>(x, A_im);
    cvt_bf16<<<(768*768 + 255)/256, 256, 0, stream>>>(conv_w, conv_wt, 768*768);
    gemm_mfma<<<dim3(768/128, M_ROWS/128), 256, 0, stream>>>(
        A_im, conv_wt, conv_b, nullptr, pos,
        h, nullptr, nullptr, nullptr, nullptr,
        M_ROWS, 768, 768, 0, 0);

    for (int L = 0; L < 4; ++L) {
        transpose_cvt<<<dim3(2304/32, 768/32), tblk, 0, stream>>>(
            qkv_w + (size_t)L*768*2304, qkv_wt, 768, 2304);
        transpose_cvt<<<dim3(768/32, 768/32), tblk, 0, stream>>>(
            proj_w + (size_t)L*768*768, proj_wt, 768, 768);
        transpose_cvt<<<dim3(MLPD/32, 768/32), tblk, 0, stream>>>(
            fc1_w + (size_t)L*768*MLPD, fc1_wt, 768, MLPD);
        transpose_cvt<<<dim3(768/32, MLPD/32), tblk, 0, stream>>>(
            fc2_w + (size_t)L*MLPD*768, fc2_wt, MLPD, 768);

        layernorm_bf16<<<M_ROWS, 256, 0, stream>>>(h, ln1_w + L*EMBED, ln1_b + L*EMBED, x_ln);

        // qkv GEMM with permuting epilogue
        gemm_mfma<<<dim3(2304/128, M_ROWS/128), 256, 0, stream>>>(
            x_ln, qkv_wt, qkv_b + (size_t)L*3*EMBED, nullptr, nullptr,
            nullptr, nullptr, q_perm, k_perm, vt_perm,
            M_ROWS, 2304, 768, 0, 2);

        attention_mfma<<<48*16, 256, 0, stream>>>(
            q_perm, k_perm, vt_perm,
            rph + (size_t)L*63*64, rpw + (size_t)L*63*64, attn_o);

        gemm_mfma<<<dim3(768/128, M_ROWS/128), 256, 0, stream>>>(
            attn_o, proj_wt, proj_b + (size_t)L*EMBED, h, nullptr,
            h, nullptr, nullptr, nullptr, nullptr,
            M_ROWS, 768, 768, 0, 0);

        layernorm_bf16<<<M_ROWS, 256, 0, stream>>>(h, ln2_w + L*EMBED, ln2_b + L*EMBED, x_ln);

        gemm_mfma<<<dim3(MLPD/128, M_ROWS/128), 256, 0, stream>>>(
            x_ln, fc1_wt, fc1_b + (size_t)L*MLPD, nullptr, nullptr,
            nullptr, mlp, nullptr, nullptr, nullptr,
            M_ROWS, MLPD, 768, 1, 1);

        gemm_mfma<<<dim3(768/128, M_ROWS/128), 256, 0, stream>>>(
            mlp, fc2_wt, fc2_b + (size_t)L*EMBED, h, nullptr,
            h, nullptr, nullptr, nullptr, nullptr,
            M_ROWS, 768, MLPD, 0, 0);
    }

    copy_out<<<(M_ROWS*EMBED + 255)/256, 256, 0, stream>>>(
        h, (float*)d_out, M_ROWS*EMBED);
}

// Round 5
// 1301.977 us; speedup vs baseline: 13.3092x; 1.2437x over previous
//
#include <hip/hip_runtime.h>
#include <hip/hip_bf16.h>
#include <math.h>
#include <stdint.h>

#define EMBED 768
#define NTOK  1024   // 32*32
#define BATCH 4
#define NHEAD 12
#define HD    64
#define MLPD  3072
#define M_ROWS 4096  // BATCH*NTOK

typedef __attribute__((ext_vector_type(8))) short short8;   // 8 x bf16 (4 VGPRs)
typedef __attribute__((ext_vector_type(4))) float floatx4;

__device__ __forceinline__ float b2f(__hip_bfloat16 v) { return __bfloat162float(v); }

// async global->LDS, 16B per lane (GEMM staging only; layout is lane-contiguous).
__device__ __forceinline__ void gld_lds16(const void* g, void* l) {
    __builtin_amdgcn_global_load_lds(
        (const __attribute__((address_space(1))) uint32_t*)g,
        (__attribute__((address_space(3))) uint32_t*)l, 16, 0, 0);
}

// XOR swizzle: chunk c (8 bf16 = 16B) of row r lives at element r*64 + ((c^(r&7))*8).
// Makes both the lane-per-row ds_write_b128 staging and the row-per-lane
// ds_read_b128 fragment reads conflict-free (each 8/16-lane phase covers 32 banks).
__device__ __forceinline__ int swz(int row, int c) { return row*64 + (((c) ^ (row & 7)) << 3); }

// ---------------- im2col: x (4,3,512,512) fp32 -> A_im (4096,768) bf16 --------------
__global__ __launch_bounds__(256)
void im2col(const float* __restrict__ x, __hip_bfloat16* __restrict__ A)
{
    int p  = blockIdx.x;
    int b  = p >> 10;
    int n  = p & 1023;
    int gh = n >> 5, gw = n & 31;
    int tid = threadIdx.x;
    for (int i = tid; i < 768; i += 256) {
        int ci = i >> 8, r = i & 255, kh = r >> 4, kw = r & 15;
        A[(size_t)p*768 + i] = __float2bfloat16(
            x[(((size_t)b*3 + ci)*512 + (gh*16 + kh))*512 + gw*16 + kw]);
    }
}

// ---------------- elementwise fp32 -> bf16 cast -------------------------------------
__global__ __launch_bounds__(256)
void cvt_bf16(const float* __restrict__ in, __hip_bfloat16* __restrict__ out, int n)
{
    int i = blockIdx.x*256 + threadIdx.x;
    if (i < n) out[i] = __float2bfloat16(in[i]);
}

// ---------------- layernorm: fp32 in -> bf16 out ------------------------------------
__global__ __launch_bounds__(256)
void layernorm_bf16(const float* __restrict__ in,
                    const float* __restrict__ w,
                    const float* __restrict__ b,
                    __hip_bfloat16* __restrict__ out)
{
    int row = blockIdx.x;
    const float* xr = in + (size_t)row*768;
    int tid = threadIdx.x;
    float s = 0.f, ss = 0.f;
    for (int i = tid; i < 768; i += 256) { float v = xr[i]; s += v; ss += v*v; }
    __shared__ float rs[256], rss[256];
    rs[tid] = s; rss[tid] = ss; __syncthreads();
    for (int o = 128; o > 0; o >>= 1) {
        if (tid < o) { rs[tid] += rs[tid+o]; rss[tid] += rss[tid+o]; }
        __syncthreads();
    }
    float mean = rs[0] * (1.f/768.f);
    float var  = rss[0] * (1.f/768.f) - mean*mean;
    float inv  = rsqrtf(var + 1e-5f);
    for (int i = tid; i < 768; i += 256)
        out[(size_t)row*768 + i] = __float2bfloat16((xr[i]-mean)*inv*w[i] + b[i]);
}

// ---------------- merged weight prep: 4 transposes in one launch --------------------
// fp32 W[K][N] -> bf16 Wt[N][K], 32x32 tiles.
__global__ __launch_bounds__(256)
void prep_weights(const float* __restrict__ qkv_w,  const float* __restrict__ proj_w,
                  const float* __restrict__ fc1_w,  const float* __restrict__ fc2_w,
                  __hip_bfloat16* __restrict__ qkv_wt, __hip_bfloat16* __restrict__ proj_wt,
                  __hip_bfloat16* __restrict__ fc1_wt, __hip_bfloat16* __restrict__ fc2_wt)
{
    int id = blockIdx.x;
    const float* src; __hip_bfloat16* dst; int K, N, bx, by;
    if (id < 1728)      {            src = qkv_w;  dst = qkv_wt;  K = 768;  N = 2304; bx = id % 72; by = id / 72; }
    else if (id < 2304) { id -= 1728; src = proj_w; dst = proj_wt; K = 768;  N = 768;  bx = id % 24; by = id / 24; }
    else if (id < 4608) { id -= 2304; src = fc1_w;  dst = fc1_wt;  K = 768;  N = 3072; bx = id % 96; by = id / 96; }
    else                { id -= 4608; src = fc2_w;  dst = fc2_wt;  K = 3072; N = 768;  bx = id % 24; by = id / 24; }

    __shared__ float t[32][33];
    int n0 = bx*32, k0 = by*32;
    int tx = threadIdx.x & 31, ty = threadIdx.x >> 5;   // (32, 8)
    #pragma unroll
    for (int r = 0; r < 4; ++r) {
        int row = ty + r*8;
        t[row][tx] = src[(size_t)(k0+row)*N + n0 + tx];
    }
    __syncthreads();
    #pragma unroll
    for (int r = 0; r < 4; ++r) {
        int row = ty + r*8;
        dst[(size_t)(n0+row)*K + k0 + tx] = __float2bfloat16(t[tx][row]);
    }
}

// ---------------- MFMA GEMM: C[M,N] = epi(A[M,K] @ Bt[N,K]^T + bias) ----------------
// emode 0: fp32 out Cf (+res, +posadd) ; emode 1: bf16 out Cb (gelu) ;
// emode 2: qkv permute -> qp/kp [bh][n][64] bf16, vp [bh][64][n] bf16.
__global__ __launch_bounds__(256)
void gemm_mfma(const __hip_bfloat16* __restrict__ A,
               const __hip_bfloat16* __restrict__ Bt,
               const float* __restrict__ bias,
               const float* __restrict__ res,
               const float* __restrict__ posadd,
               float* __restrict__ Cf,
               __hip_bfloat16* __restrict__ Cb,
               __hip_bfloat16* __restrict__ qp,
               __hip_bfloat16* __restrict__ kp,
               __hip_bfloat16* __restrict__ vp,
               int M, int N, int K, int dogelu, int emode)
{
    __shared__ __align__(16) __hip_bfloat16 As[128*32];
    __shared__ __align__(16) __hip_bfloat16 Bs[128*32];

    const int tid  = threadIdx.x;
    const int lane = tid & 63;
    const int wid  = tid >> 6;
    const int wr   = wid >> 1;
    const int wc   = wid & 1;
    const int lr   = lane & 15;
    const int quad = lane >> 4;

    const int bm = blockIdx.y * 128;
    const int bn = blockIdx.x * 128;

    const int srow  = tid >> 2;
    const int skoff = (tid & 3) * 8;
    const int wbase = wid * 1024;      // bytes

    floatx4 acc[4][4];
    #pragma unroll
    for (int i = 0; i < 4; ++i)
        #pragma unroll
        for (int j = 0; j < 4; ++j)
            acc[i][j] = (floatx4){0.f,0.f,0.f,0.f};

    for (int k0 = 0; k0 < K; k0 += 32) {
        #pragma unroll
        for (int c = 0; c < 2; ++c) {
            gld_lds16(A  + (size_t)(bm + c*64 + srow)*K + k0 + skoff,
                      (char*)As + c*4096 + wbase);
            gld_lds16(Bt + (size_t)(bn + c*64 + srow)*K + k0 + skoff,
                      (char*)Bs + c*4096 + wbase);
        }
        __syncthreads();

        short8 a[4], b[4];
        #pragma unroll
        for (int i = 0; i < 4; ++i)
            a[i] = *(const short8*)((const void*)(As + (wr*64 + i*16 + lr)*32 + quad*8));
        #pragma unroll
        for (int j = 0; j < 4; ++j)
            b[j] = *(const short8*)((const void*)(Bs + (wc*64 + j*16 + lr)*32 + quad*8));
        #pragma unroll
        for (int i = 0; i < 4; ++i)
            #pragma unroll
            for (int j = 0; j < 4; ++j)
                acc[i][j] = __builtin_amdgcn_mfma_f32_16x16x32_bf16(a[i], b[j], acc[i][j], 0, 0, 0);
        __syncthreads();
    }

    // epilogue: C/D layout col=lane&15, row=quad*4+reg
    #pragma unroll
    for (int j = 0; j < 4; ++j) {
        int col = bn + wc*64 + j*16 + lr;
        float bs = bias[col];
        #pragma unroll
        for (int i = 0; i < 4; ++i) {
            #pragma unroll
            for (int r = 0; r < 4; ++r) {
                int row = bm + wr*64 + i*16 + quad*4 + r;
                float val = acc[i][j][r] + bs;
                if (emode == 2) {
                    int which = col / 768;
                    int hd    = col % 768;
                    int head  = hd >> 6;
                    int d     = hd & 63;
                    int b_    = row >> 10;
                    int n_    = row & 1023;
                    int bh    = b_*NHEAD + head;
                    __hip_bfloat16 bv = __float2bfloat16(val);
                    if      (which == 0) qp[((size_t)bh*NTOK + n_)*HD + d] = bv;
                    else if (which == 1) kp[((size_t)bh*NTOK + n_)*HD + d] = bv;
                    else                 vp[((size_t)bh*HD + d)*NTOK + n_] = bv;
                } else {
                    if (dogelu) val = 0.5f*val*(1.f + erff(val*0.70710678118f));
                    if (res)    val += res[(size_t)row*N + col];
                    if (posadd) val += posadd[(size_t)(row & 1023)*N + col];
                    if (emode == 0) Cf[(size_t)row*N + col] = val;
                    else            Cb[(size_t)row*N + col] = __float2bfloat16(val);
                }
            }
        }
    }
}

// ---------------- MFMA flash attention, swizzled LDS, shift-free softmax ------------
// grid = 48 (b,h) * 16 q-tiles. 4 waves; wave w owns queries [w*16, w*16+16).
__global__ __launch_bounds__(256)
void attention_mfma(const __hip_bfloat16* __restrict__ qp,   // [48][1024][64]
                    const __hip_bfloat16* __restrict__ kp,   // [48][1024][64]
                    const __hip_bfloat16* __restrict__ vp,   // [48][64][1024] (V^T)
                    const float* __restrict__ rph,           // (63,64) this layer
                    const float* __restrict__ rpw,           // (63,64)
                    __hip_bfloat16* __restrict__ out)        // (4,1024,768) bf16
{
    const int blk  = blockIdx.x;
    const int bh   = blk >> 4;
    const int qt   = blk & 15;
    const int b    = bh / NHEAD;
    const int head = bh % NHEAD;
    const int tid  = threadIdx.x;
    const int lane = tid & 63;
    const int w    = tid >> 6;
    const int lr   = lane & 15;
    const int quad = lane >> 4;

    // All tiles: 64 rows x 64 bf16 (128 B), XOR-swizzled chunks.
    __shared__ __align__(16) __hip_bfloat16 Qs[64*64];
    __shared__ __align__(16) __hip_bfloat16 Ks[64*64];      // prologue alias: rph table
    __shared__ __align__(16) __hip_bfloat16 Vs[64*64];      // prologue alias: rpw table
    __shared__ __align__(16) __hip_bfloat16 Ps[4*16*64];    // per-wave P tiles
    __shared__ float relhS[64*32];                          // [qlocal][kh]
    __shared__ float relwS[64*32];                          // [qlocal][kw]

    const __hip_bfloat16* qb = qp + ((size_t)bh*NTOK + qt*64)*HD;
    const __hip_bfloat16* kb = kp + (size_t)bh*NTOK*HD;
    const __hip_bfloat16* vb = vp + (size_t)bh*HD*NTOK;

    // staging geometry: thread handles row sr, chunks sc, sc+1 (32 B contiguous)
    const int sr = tid >> 2;
    const int sc = (tid & 3) * 2;

    // ---- issue K/V prefetch for kt=0 (latency hidden under prologue) ----
    short8 kreg0, kreg1, vreg0, vreg1;
    {
        const __hip_bfloat16* kk = kb + (size_t)sr*HD + sc*8;
        kreg0 = *(const short8*)((const void*)kk);
        kreg1 = *(const short8*)((const void*)(kk + 8));
        const __hip_bfloat16* vv = vb + (size_t)sr*NTOK + sc*8;
        vreg0 = *(const short8*)((const void*)vv);
        vreg1 = *(const short8*)((const void*)(vv + 8));
    }

    // ---- stage Q (swizzled) ----
    {
        const __hip_bfloat16* qq = qb + (size_t)sr*HD + sc*8;
        short8 q0 = *(const short8*)((const void*)qq);
        short8 q1 = *(const short8*)((const void*)(qq + 8));
        *(short8*)((void*)(Qs + swz(sr, sc)))   = q0;
        *(short8*)((void*)(Qs + swz(sr, sc+1))) = q1;
    }

    // ---- stage rel-pos tables (fp32 global -> bf16 LDS, swizzled) ----
    for (int i = tid; i < 504; i += 256) {
        int r = i >> 3, c = i & 7;
        const float* ph = rph + (size_t)r*HD + c*8;
        const float* pw = rpw + (size_t)r*HD + c*8;
        union { short8 v; __hip_bfloat16 e[8]; } uh, uw;
        #pragma unroll
        for (int e = 0; e < 8; ++e) { uh.e[e] = __float2bfloat16(ph[e]); uw.e[e] = __float2bfloat16(pw[e]); }
        *(short8*)((void*)(Ks + swz(r, c))) = uh.v;
        *(short8*)((void*)(Vs + swz(r, c))) = uw.v;
    }
    if (tid < 16) {   // zero pad-row 63 of both tables
        short8 z = (short8){0,0,0,0,0,0,0,0};
        int c = tid & 7;
        if (tid < 8) *(short8*)((void*)(Ks + swz(63, c))) = z;
        else         *(short8*)((void*)(Vs + swz(63, c))) = z;
    }
    __syncthreads();

    // ---- Q fragments (reused all k-tiles) ----
    short8 qa0 = *(const short8*)((const void*)(Qs + swz(w*16 + lr, quad)));
    short8 qa1 = *(const short8*)((const void*)(Qs + swz(w*16 + lr, 4 + quad)));

    const int qrow = w*16 + quad*4;           // +rr = local query row
    const int qh_  = qt*2 + (w >> 1);         // grid row (uniform per wave)
    const int qw_  = (w & 1)*16 + quad*4;     // +rr = grid col

    // ---- rel-pos via MFMA + C-layout scatter ----
    #pragma unroll
    for (int j = 0; j < 4; ++j) {
        int t = j*16 + lr;
        short8 th0 = *(const short8*)((const void*)(Ks + swz(j*16 + lr, quad)));
        short8 th1 = *(const short8*)((const void*)(Ks + swz(j*16 + lr, 4 + quad)));
        floatx4 ha = (floatx4){0.f,0.f,0.f,0.f};
        ha = __builtin_amdgcn_mfma_f32_16x16x32_bf16(qa0, th0, ha, 0, 0, 0);
        ha = __builtin_amdgcn_mfma_f32_16x16x32_bf16(qa1, th1, ha, 0, 0, 0);
        short8 tw0 = *(const short8*)((const void*)(Vs + swz(j*16 + lr, quad)));
        short8 tw1 = *(const short8*)((const void*)(Vs + swz(j*16 + lr, 4 + quad)));
        floatx4 wa = (floatx4){0.f,0.f,0.f,0.f};
        wa = __builtin_amdgcn_mfma_f32_16x16x32_bf16(qa0, tw0, wa, 0, 0, 0);
        wa = __builtin_amdgcn_mfma_f32_16x16x32_bf16(qa1, tw1, wa, 0, 0, 0);
        int kh = qh_ + 31 - t;
        #pragma unroll
        for (int rr = 0; rr < 4; ++rr) {
            if (kh >= 0 && kh < 32) relhS[(qrow + rr)*32 + kh] = ha[rr];
            int kw = qw_ + rr + 31 - t;
            if (kw >= 0 && kw < 32) relwS[(qrow + rr)*32 + kw] = wa[rr];
        }
    }

    // per-lane rel-w (intra-wave dependency; kw = (j&1)*16 + lr)
    float rw[4][2];
    #pragma unroll
    for (int rr = 0; rr < 4; ++rr)
        #pragma unroll
        for (int jp = 0; jp < 2; ++jp)
            rw[rr][jp] = relwS[(qrow + rr)*32 + jp*16 + lr];

    floatx4 o[4];
    #pragma unroll
    for (int ds = 0; ds < 4; ++ds) o[ds] = (floatx4){0.f,0.f,0.f,0.f};
    float lsum[4] = {0.f, 0.f, 0.f, 0.f};

    const float scale = 0.125f;

    for (int kt = 0; kt < 16; ++kt) {
        __syncthreads();   // prior-iter (or prologue table) reads of Ks/Vs done
        *(short8*)((void*)(Ks + swz(sr, sc)))   = kreg0;
        *(short8*)((void*)(Ks + swz(sr, sc+1))) = kreg1;
        *(short8*)((void*)(Vs + swz(sr, sc)))   = vreg0;
        *(short8*)((void*)(Vs + swz(sr, sc+1))) = vreg1;
        __syncthreads();

        if (kt < 15) {  // prefetch next tile; overlaps the whole compute phase
            const __hip_bfloat16* kk = kb + (size_t)(kt+1)*64*HD + (size_t)sr*HD + sc*8;
            kreg0 = *(const short8*)((const void*)kk);
            kreg1 = *(const short8*)((const void*)(kk + 8));
            const __hip_bfloat16* vv = vb + (size_t)sr*NTOK + (kt+1)*64 + sc*8;
            vreg0 = *(const short8*)((const void*)vv);
            vreg1 = *(const short8*)((const void*)(vv + 8));
        }

        // relh for this k-tile (broadcast reads: address uniform in lr)
        float2 rh2[4];
        #pragma unroll
        for (int rr = 0; rr < 4; ++rr)
            rh2[rr] = *(const float2*)((const void*)(relhS + (qrow + rr)*32 + kt*2));

        // S = Q K^T
        floatx4 sv[4];
        #pragma unroll
        for (int j = 0; j < 4; ++j) {
            short8 kb0 = *(const short8*)((const void*)(Ks + swz(j*16 + lr, quad)));
            short8 kb1 = *(const short8*)((const void*)(Ks + swz(j*16 + lr, 4 + quad)));
            floatx4 z = (floatx4){0.f,0.f,0.f,0.f};
            z = __builtin_amdgcn_mfma_f32_16x16x32_bf16(qa0, kb0, z, 0, 0, 0);
            z = __builtin_amdgcn_mfma_f32_16x16x32_bf16(qa1, kb1, z, 0, 0, 0);
            sv[j] = z;
        }

        // P = exp(clamp(s)) ; accumulate denominator ; write P (swizzled, per-wave)
        #pragma unroll
        for (int j = 0; j < 4; ++j) {
            int colc = j*2 + (lr >> 3);
            #pragma unroll
            for (int rr = 0; rr < 4; ++rr) {
                float s = sv[j][rr]*scale + ((j < 2) ? rh2[rr].x : rh2[rr].y) + rw[rr][j & 1];
                s = fminf(fmaxf(s, -60.f), 60.f);
                float pp = __expf(s);
                lsum[rr] += pp;
                int prow = quad*4 + rr;
                Ps[w*1024 + prow*64 + ((colc ^ (prow & 7)) << 3) + (lr & 7)] = __float2bfloat16(pp);
            }
        }

        // O += P V  (P read is intra-wave; compiler inserts lgkm wait)
        short8 pa0 = *(const short8*)((const void*)(Ps + w*1024 + swz(lr, quad)));
        short8 pa1 = *(const short8*)((const void*)(Ps + w*1024 + swz(lr, 4 + quad)));
        #pragma unroll
        for (int ds = 0; ds < 4; ++ds) {
            short8 v0 = *(const short8*)((const void*)(Vs + swz(ds*16 + lr, quad)));
            short8 v1 = *(const short8*)((const void*)(Vs + swz(ds*16 + lr, 4 + quad)));
            o[ds] = __builtin_amdgcn_mfma_f32_16x16x32_bf16(pa0, v0, o[ds], 0, 0, 0);
            o[ds] = __builtin_amdgcn_mfma_f32_16x16x32_bf16(pa1, v1, o[ds], 0, 0, 0);
        }
    }

    // denominator reduce across the 16 lanes of each row, then write
    #pragma unroll
    for (int off = 1; off < 16; off <<= 1)
        #pragma unroll
        for (int rr = 0; rr < 4; ++rr)
            lsum[rr] += __shfl_xor(lsum[rr], off, 16);

    #pragma unroll
    for (int rr = 0; rr < 4; ++rr) {
        float inv = 1.f / lsum[rr];
        int n = qt*64 + w*16 + quad*4 + rr;
        size_t base = ((size_t)b*NTOK + n)*EMBED + head*HD;
        #pragma unroll
        for (int ds = 0; ds < 4; ++ds)
            out[base + ds*16 + lr] = __float2bfloat16(o[ds][rr] * inv);
    }
}

// ---------------- output copy -------------------------------------------------------
__global__ __launch_bounds__(256)
void copy_out(const float* __restrict__ in, float* __restrict__ out, int n)
{
    int i = blockIdx.x*256 + threadIdx.x;
    if (i < n) out[i] = in[i];
}

extern "C" void kernel_launch(void* const* d_in, const int* in_sizes, int n_in,
                              void* d_out, int out_size, void* d_ws, size_t ws_size,
                              hipStream_t stream)
{
    const float* x      = (const float*)d_in[0];
    const float* conv_w = (const float*)d_in[1];
    const float* conv_b = (const float*)d_in[2];
    const float* pos    = (const float*)d_in[3];
    const float* ln1_w  = (const float*)d_in[4];
    const float* ln1_b  = (const float*)d_in[5];
    const float* qkv_w  = (const float*)d_in[6];
    const float* qkv_b  = (const float*)d_in[7];
    const float* proj_w = (const float*)d_in[8];
    const float* proj_b = (const float*)d_in[9];
    const float* rph    = (const float*)d_in[10];
    const float* rpw    = (const float*)d_in[11];
    const float* ln2_w  = (const float*)d_in[12];
    const float* ln2_b  = (const float*)d_in[13];
    const float* fc1_w  = (const float*)d_in[14];
    const float* fc1_b  = (const float*)d_in[15];
    const float* fc2_w  = (const float*)d_in[16];
    const float* fc2_b  = (const float*)d_in[17];

    char* p = (char*)d_ws;
    float*           h       = (float*)p;           p += (size_t)M_ROWS*EMBED*4;
    __hip_bfloat16*  q_perm  = (__hip_bfloat16*)p;  p += (size_t)48*NTOK*HD*2;
    __hip_bfloat16*  k_perm  = (__hip_bfloat16*)p;  p += (size_t)48*NTOK*HD*2;
    __hip_bfloat16*  vt_perm = (__hip_bfloat16*)p;  p += (size_t)48*NTOK*HD*2;
    __hip_bfloat16*  x_ln    = (__hip_bfloat16*)p;  p += (size_t)M_ROWS*EMBED*2;
    __hip_bfloat16*  attn_o  = (__hip_bfloat16*)p;  p += (size_t)M_ROWS*EMBED*2;
    __hip_bfloat16*  mlp     = (__hip_bfloat16*)p;  p += (size_t)M_ROWS*MLPD*2;
    __hip_bfloat16*  qkv_wt  = (__hip_bfloat16*)p;  p += (size_t)2304*768*2;
    __hip_bfloat16*  proj_wt = (__hip_bfloat16*)p;  p += (size_t)768*768*2;
    __hip_bfloat16*  fc1_wt  = (__hip_bfloat16*)p;  p += (size_t)MLPD*768*2;
    __hip_bfloat16*  fc2_wt  = (__hip_bfloat16*)p;  p += (size_t)768*MLPD*2;

    __hip_bfloat16*  A_im    = mlp;      // alias: not simultaneously live
    __hip_bfloat16*  conv_wt = qkv_wt;   // alias: overwritten by layer-0 prep

    // ---- patch embed as GEMM ----
    im2col<<<M_ROWS, 256, 0, stream>>>(x, A_im);
    cvt_bf16<<<(768*768 + 255)/256, 256, 0, stream>>>(conv_w, conv_wt, 768*768);
    gemm_mfma<<<dim3(768/128, M_ROWS/128), 256, 0, stream>>>(
        A_im, conv_wt, conv_b, nullptr, pos,
        h, nullptr, nullptr, nullptr, nullptr,
        M_ROWS, 768, 768, 0, 0);

    for (int L = 0; L < 4; ++L) {
        prep_weights<<<6912, 256, 0, stream>>>(
            qkv_w + (size_t)L*768*2304, proj_w + (size_t)L*768*768,
            fc1_w + (size_t)L*768*MLPD, fc2_w + (size_t)L*MLPD*768,
            qkv_wt, proj_wt, fc1_wt, fc2_wt);

        layernorm_bf16<<<M_ROWS, 256, 0, stream>>>(h, ln1_w + L*EMBED, ln1_b + L*EMBED, x_ln);

        gemm_mfma<<<dim3(2304/128, M_ROWS/128), 256, 0, stream>>>(
            x_ln, qkv_wt, qkv_b + (size_t)L*3*EMBED, nullptr, nullptr,
            nullptr, nullptr, q_perm, k_perm, vt_perm,
            M_ROWS, 2304, 768, 0, 2);

        attention_mfma<<<48*16, 256, 0, stream>>>(
            q_perm, k_perm, vt_perm,
            rph + (size_t)L*63*64, rpw + (size_t)L*63*64, attn_o);

        gemm_mfma<<<dim3(768/128, M_ROWS/128), 256, 0, stream>>>(
            attn_o, proj_wt, proj_b + (size_t)L*EMBED, h, nullptr,
            h, nullptr, nullptr, nullptr, nullptr,
            M_ROWS, 768, 768, 0, 0);

        layernorm_bf16<<<M_ROWS, 256, 0, stream>>>(h, ln2_w + L*EMBED, ln2_b + L*EMBED, x_ln);

        gemm_mfma<<<dim3(MLPD/128, M_ROWS/128), 256, 0, stream>>>(
            x_ln, fc1_wt, fc1_b + (size_t)L*MLPD, nullptr, nullptr,
            nullptr, mlp, nullptr, nullptr, nullptr,
            M_ROWS, MLPD, 768, 1, 1);

        gemm_mfma<<<dim3(768/128, M_ROWS/128), 256, 0, stream>>>(
            mlp, fc2_wt, fc2_b + (size_t)L*EMBED, h, nullptr,
            h, nullptr, nullptr, nullptr, nullptr,
            M_ROWS, 768, MLPD, 0, 0);
    }

    copy_out<<<(M_ROWS*EMBED + 255)/256, 256, 0, stream>>>(
        h, (float*)d_out, M_ROWS*EMBED);
}

// Round 6
// 1087.573 us; speedup vs baseline: 15.9330x; 1.1971x over previous
//
#include <hip/hip_runtime.h>
#include <hip/hip_bf16.h>
#include <math.h>
#include <stdint.h>

#define EMBED 768
#define NTOK  1024   // 32*32
#define BATCH 4
#define NHEAD 12
#define HD    64
#define MLPD  3072
#define M_ROWS 4096  // BATCH*NTOK

typedef __attribute__((ext_vector_type(8))) short short8;   // 8 x bf16 (4 VGPRs)
typedef __attribute__((ext_vector_type(4))) float floatx4;

__device__ __forceinline__ float b2f(__hip_bfloat16 v) { return __bfloat162float(v); }

// async global->LDS, 16B per lane (GEMM staging; layout lane-contiguous).
__device__ __forceinline__ void gld_lds16(const void* g, void* l) {
    __builtin_amdgcn_global_load_lds(
        (const __attribute__((address_space(1))) uint32_t*)g,
        (__attribute__((address_space(3))) uint32_t*)l, 16, 0, 0);
}

// XOR swizzle for attention tiles: chunk c (8 bf16) of row r at r*64 + ((c^(r&7))*8).
__device__ __forceinline__ int swz(int row, int c) { return row*64 + (((c) ^ (row & 7)) << 3); }

// ---------------- im2col: x (4,3,512,512) fp32 -> A_im (4096,768) bf16 --------------
__global__ __launch_bounds__(256)
void im2col(const float* __restrict__ x, __hip_bfloat16* __restrict__ A)
{
    int p  = blockIdx.x;
    int b  = p >> 10;
    int n  = p & 1023;
    int gh = n >> 5, gw = n & 31;
    int tid = threadIdx.x;
    for (int i = tid; i < 768; i += 256) {
        int ci = i >> 8, r = i & 255, kh = r >> 4, kw = r & 15;
        A[(size_t)p*768 + i] = __float2bfloat16(
            x[(((size_t)b*3 + ci)*512 + (gh*16 + kh))*512 + gw*16 + kw]);
    }
}

// ---------------- elementwise fp32 -> bf16 cast -------------------------------------
__global__ __launch_bounds__(256)
void cvt_bf16(const float* __restrict__ in, __hip_bfloat16* __restrict__ out, int n)
{
    int i = blockIdx.x*256 + threadIdx.x;
    if (i < n) out[i] = __float2bfloat16(in[i]);
}

// ---------------- layernorm: fp32 in -> bf16 out ------------------------------------
__global__ __launch_bounds__(256)
void layernorm_bf16(const float* __restrict__ in,
                    const float* __restrict__ w,
                    const float* __restrict__ b,
                    __hip_bfloat16* __restrict__ out)
{
    int row = blockIdx.x;
    const float* xr = in + (size_t)row*768;
    int tid = threadIdx.x;
    float v0 = xr[tid], v1 = xr[tid+256], v2 = xr[tid+512];
    float s = v0+v1+v2, ss = v0*v0+v1*v1+v2*v2;
    __shared__ float rs[256], rss[256];
    rs[tid] = s; rss[tid] = ss; __syncthreads();
    for (int o = 128; o > 0; o >>= 1) {
        if (tid < o) { rs[tid] += rs[tid+o]; rss[tid] += rss[tid+o]; }
        __syncthreads();
    }
    float mean = rs[0] * (1.f/768.f);
    float var  = rss[0] * (1.f/768.f) - mean*mean;
    float inv  = rsqrtf(var + 1e-5f);
    out[(size_t)row*768 + tid]     = __float2bfloat16((v0-mean)*inv*w[tid]     + b[tid]);
    out[(size_t)row*768 + tid+256] = __float2bfloat16((v1-mean)*inv*w[tid+256] + b[tid+256]);
    out[(size_t)row*768 + tid+512] = __float2bfloat16((v2-mean)*inv*w[tid+512] + b[tid+512]);
}

// ---------------- fused: h += p0+p1+bias ; x_ln = LN(h) (next layer ln1) ------------
__global__ __launch_bounds__(256)
void resum_ln(float* __restrict__ h,
              const float* __restrict__ p0, const float* __restrict__ p1,
              const float* __restrict__ bias,
              const float* __restrict__ w, const float* __restrict__ b,
              __hip_bfloat16* __restrict__ out)
{
    int row = blockIdx.x;
    int tid = threadIdx.x;
    size_t base = (size_t)row*768;
    float v[3];
    float s = 0.f, ss = 0.f;
    #pragma unroll
    for (int e = 0; e < 3; ++e) {
        int i = tid + e*256;
        float val = h[base+i] + p0[base+i] + p1[base+i] + bias[i];
        h[base+i] = val;
        v[e] = val; s += val; ss += val*val;
    }
    __shared__ float rs[256], rss[256];
    rs[tid] = s; rss[tid] = ss; __syncthreads();
    for (int o = 128; o > 0; o >>= 1) {
        if (tid < o) { rs[tid] += rs[tid+o]; rss[tid] += rss[tid+o]; }
        __syncthreads();
    }
    float mean = rs[0] * (1.f/768.f);
    float var  = rss[0] * (1.f/768.f) - mean*mean;
    float inv  = rsqrtf(var + 1e-5f);
    #pragma unroll
    for (int e = 0; e < 3; ++e) {
        int i = tid + e*256;
        out[base+i] = __float2bfloat16((v[e]-mean)*inv*w[i] + b[i]);
    }
}

// ---------------- final: out = h + p0 + p1 + bias (fp32) ----------------------------
__global__ __launch_bounds__(256)
void resum_out(const float* __restrict__ h,
               const float* __restrict__ p0, const float* __restrict__ p1,
               const float* __restrict__ bias,
               float* __restrict__ out)
{
    int i = blockIdx.x*256 + threadIdx.x;
    out[i] = h[i] + p0[i] + p1[i] + bias[i % 768];
}

// ---------------- merged weight prep: 4 transposes in one launch --------------------
__global__ __launch_bounds__(256)
void prep_weights(const float* __restrict__ qkv_w,  const float* __restrict__ proj_w,
                  const float* __restrict__ fc1_w,  const float* __restrict__ fc2_w,
                  __hip_bfloat16* __restrict__ qkv_wt, __hip_bfloat16* __restrict__ proj_wt,
                  __hip_bfloat16* __restrict__ fc1_wt, __hip_bfloat16* __restrict__ fc2_wt)
{
    int id = blockIdx.x;
    const float* src; __hip_bfloat16* dst; int K, N, bx, by;
    if (id < 1728)      {            src = qkv_w;  dst = qkv_wt;  K = 768;  N = 2304; bx = id % 72; by = id / 72; }
    else if (id < 2304) { id -= 1728; src = proj_w; dst = proj_wt; K = 768;  N = 768;  bx = id % 24; by = id / 24; }
    else if (id < 4608) { id -= 2304; src = fc1_w;  dst = fc1_wt;  K = 768;  N = 3072; bx = id % 96; by = id / 96; }
    else                { id -= 4608; src = fc2_w;  dst = fc2_wt;  K = 3072; N = 768;  bx = id % 24; by = id / 24; }

    __shared__ float t[32][33];
    int n0 = bx*32, k0 = by*32;
    int tx = threadIdx.x & 31, ty = threadIdx.x >> 5;   // (32, 8)
    #pragma unroll
    for (int r = 0; r < 4; ++r) {
        int row = ty + r*8;
        t[row][tx] = src[(size_t)(k0+row)*N + n0 + tx];
    }
    __syncthreads();
    #pragma unroll
    for (int r = 0; r < 4; ++r) {
        int row = ty + r*8;
        dst[(size_t)(n0+row)*K + k0 + tx] = __float2bfloat16(t[tx][row]);
    }
}

// ---------------- MFMA GEMM, 64x128 tile: C = epi(A[M,K] @ Bt[N,K]^T) ---------------
// grid (N/128, M/64, S). 4 waves 2x2: wave = 32 rows x 64 cols (2x4 mfma accs).
// emode 0: fp32 Cf (+res, +posadd) ; 1: bf16 Cb (+gelu) ; 2: qkv permute ;
// emode 3: fp32 partial -> Cf + z*M*N (no bias; K-split over blockIdx.z).
__global__ __launch_bounds__(256)
void gemm64(const __hip_bfloat16* __restrict__ A,
            const __hip_bfloat16* __restrict__ Bt,
            const float* __restrict__ bias,
            const float* __restrict__ res,
            const float* __restrict__ posadd,
            float* __restrict__ Cf,
            __hip_bfloat16* __restrict__ Cb,
            __hip_bfloat16* __restrict__ qp,
            __hip_bfloat16* __restrict__ kp,
            __hip_bfloat16* __restrict__ vp,
            int M, int N, int K, int S, int dogelu, int emode)
{
    __shared__ __align__(16) __hip_bfloat16 As[64*32];    // 4 KB
    __shared__ __align__(16) __hip_bfloat16 Bs[128*32];   // 8 KB

    const int tid  = threadIdx.x;
    const int lane = tid & 63;
    const int wid  = tid >> 6;
    const int wr   = wid >> 1;          // 0..1 : 32-row half
    const int wc   = wid & 1;           // 0..1 : 64-col half
    const int lr   = lane & 15;
    const int quad = lane >> 4;

    const int bm = blockIdx.y * 64;
    const int bn = blockIdx.x * 128;
    const int z  = blockIdx.z;
    const int Kseg = K / S;
    const int kbeg = z * Kseg;
    const int kend = kbeg + Kseg;

    const int srow  = tid >> 2;         // 0..63
    const int skoff = (tid & 3) * 8;
    const int wbase = wid * 1024;       // bytes

    floatx4 acc[2][4];
    #pragma unroll
    for (int i = 0; i < 2; ++i)
        #pragma unroll
        for (int j = 0; j < 4; ++j)
            acc[i][j] = (floatx4){0.f,0.f,0.f,0.f};

    for (int k0 = kbeg; k0 < kend; k0 += 32) {
        gld_lds16(A + (size_t)(bm + srow)*K + k0 + skoff, (char*)As + wbase);
        #pragma unroll
        for (int c = 0; c < 2; ++c)
            gld_lds16(Bt + (size_t)(bn + c*64 + srow)*K + k0 + skoff,
                      (char*)Bs + c*4096 + wbase);
        __syncthreads();

        short8 a[2], b[4];
        #pragma unroll
        for (int i = 0; i < 2; ++i)
            a[i] = *(const short8*)((const void*)(As + (wr*32 + i*16 + lr)*32 + quad*8));
        #pragma unroll
        for (int j = 0; j < 4; ++j)
            b[j] = *(const short8*)((const void*)(Bs + (wc*64 + j*16 + lr)*32 + quad*8));
        #pragma unroll
        for (int i = 0; i < 2; ++i)
            #pragma unroll
            for (int j = 0; j < 4; ++j)
                acc[i][j] = __builtin_amdgcn_mfma_f32_16x16x32_bf16(a[i], b[j], acc[i][j], 0, 0, 0);
        __syncthreads();
    }

    // epilogue: C/D layout col=lane&15, row=quad*4+reg
    #pragma unroll
    for (int j = 0; j < 4; ++j) {
        int col = bn + wc*64 + j*16 + lr;
        float bs = (emode == 3) ? 0.f : bias[col];
        #pragma unroll
        for (int i = 0; i < 2; ++i) {
            #pragma unroll
            for (int r = 0; r < 4; ++r) {
                int row = bm + wr*32 + i*16 + quad*4 + r;
                float val = acc[i][j][r] + bs;
                if (emode == 2) {
                    int which = col / 768;
                    int hd    = col % 768;
                    int head  = hd >> 6;
                    int d     = hd & 63;
                    int b_    = row >> 10;
                    int n_    = row & 1023;
                    int bh    = b_*NHEAD + head;
                    __hip_bfloat16 bv = __float2bfloat16(val);
                    if      (which == 0) qp[((size_t)bh*NTOK + n_)*HD + d] = bv;
                    else if (which == 1) kp[((size_t)bh*NTOK + n_)*HD + d] = bv;
                    else                 vp[((size_t)bh*HD + d)*NTOK + n_] = bv;
                } else if (emode == 3) {
                    Cf[(size_t)z*M*N + (size_t)row*N + col] = val;
                } else {
                    if (dogelu) val = 0.5f*val*(1.f + erff(val*0.70710678118f));
                    if (res)    val += res[(size_t)row*N + col];
                    if (posadd) val += posadd[(size_t)(row & 1023)*N + col];
                    if (emode == 0) Cf[(size_t)row*N + col] = val;
                    else            Cb[(size_t)row*N + col] = __float2bfloat16(val);
                }
            }
        }
    }
}

// ---------------- MFMA flash attention, swizzled LDS, shift-free softmax ------------
__global__ __launch_bounds__(256)
void attention_mfma(const __hip_bfloat16* __restrict__ qp,   // [48][1024][64]
                    const __hip_bfloat16* __restrict__ kp,   // [48][1024][64]
                    const __hip_bfloat16* __restrict__ vp,   // [48][64][1024] (V^T)
                    const float* __restrict__ rph,           // (63,64)
                    const float* __restrict__ rpw,           // (63,64)
                    __hip_bfloat16* __restrict__ out)        // (4,1024,768) bf16
{
    const int blk  = blockIdx.x;
    const int bh   = blk >> 4;
    const int qt   = blk & 15;
    const int b    = bh / NHEAD;
    const int head = bh % NHEAD;
    const int tid  = threadIdx.x;
    const int lane = tid & 63;
    const int w    = tid >> 6;
    const int lr   = lane & 15;
    const int quad = lane >> 4;

    __shared__ __align__(16) __hip_bfloat16 Qs[64*64];
    __shared__ __align__(16) __hip_bfloat16 Ks[64*64];      // prologue alias: rph table
    __shared__ __align__(16) __hip_bfloat16 Vs[64*64];      // prologue alias: rpw table
    __shared__ __align__(16) __hip_bfloat16 Ps[4*16*64];
    __shared__ float relhS[64*32];
    __shared__ float relwS[64*32];

    const __hip_bfloat16* qb = qp + ((size_t)bh*NTOK + qt*64)*HD;
    const __hip_bfloat16* kb = kp + (size_t)bh*NTOK*HD;
    const __hip_bfloat16* vb = vp + (size_t)bh*HD*NTOK;

    const int sr = tid >> 2;
    const int sc = (tid & 3) * 2;

    short8 kreg0, kreg1, vreg0, vreg1;
    {
        const __hip_bfloat16* kk = kb + (size_t)sr*HD + sc*8;
        kreg0 = *(const short8*)((const void*)kk);
        kreg1 = *(const short8*)((const void*)(kk + 8));
        const __hip_bfloat16* vv = vb + (size_t)sr*NTOK + sc*8;
        vreg0 = *(const short8*)((const void*)vv);
        vreg1 = *(const short8*)((const void*)(vv + 8));
    }

    {
        const __hip_bfloat16* qq = qb + (size_t)sr*HD + sc*8;
        short8 q0 = *(const short8*)((const void*)qq);
        short8 q1 = *(const short8*)((const void*)(qq + 8));
        *(short8*)((void*)(Qs + swz(sr, sc)))   = q0;
        *(short8*)((void*)(Qs + swz(sr, sc+1))) = q1;
    }

    for (int i = tid; i < 504; i += 256) {
        int r = i >> 3, c = i & 7;
        const float* ph = rph + (size_t)r*HD + c*8;
        const float* pw = rpw + (size_t)r*HD + c*8;
        union { short8 v; __hip_bfloat16 e[8]; } uh, uw;
        #pragma unroll
        for (int e = 0; e < 8; ++e) { uh.e[e] = __float2bfloat16(ph[e]); uw.e[e] = __float2bfloat16(pw[e]); }
        *(short8*)((void*)(Ks + swz(r, c))) = uh.v;
        *(short8*)((void*)(Vs + swz(r, c))) = uw.v;
    }
    if (tid < 16) {
        short8 z = (short8){0,0,0,0,0,0,0,0};
        int c = tid & 7;
        if (tid < 8) *(short8*)((void*)(Ks + swz(63, c))) = z;
        else         *(short8*)((void*)(Vs + swz(63, c))) = z;
    }
    __syncthreads();

    short8 qa0 = *(const short8*)((const void*)(Qs + swz(w*16 + lr, quad)));
    short8 qa1 = *(const short8*)((const void*)(Qs + swz(w*16 + lr, 4 + quad)));

    const int qrow = w*16 + quad*4;
    const int qh_  = qt*2 + (w >> 1);
    const int qw_  = (w & 1)*16 + quad*4;

    #pragma unroll
    for (int j = 0; j < 4; ++j) {
        int t = j*16 + lr;
        short8 th0 = *(const short8*)((const void*)(Ks + swz(j*16 + lr, quad)));
        short8 th1 = *(const short8*)((const void*)(Ks + swz(j*16 + lr, 4 + quad)));
        floatx4 ha = (floatx4){0.f,0.f,0.f,0.f};
        ha = __builtin_amdgcn_mfma_f32_16x16x32_bf16(qa0, th0, ha, 0, 0, 0);
        ha = __builtin_amdgcn_mfma_f32_16x16x32_bf16(qa1, th1, ha, 0, 0, 0);
        short8 tw0 = *(const short8*)((const void*)(Vs + swz(j*16 + lr, quad)));
        short8 tw1 = *(const short8*)((const void*)(Vs + swz(j*16 + lr, 4 + quad)));
        floatx4 wa = (floatx4){0.f,0.f,0.f,0.f};
        wa = __builtin_amdgcn_mfma_f32_16x16x32_bf16(qa0, tw0, wa, 0, 0, 0);
        wa = __builtin_amdgcn_mfma_f32_16x16x32_bf16(qa1, tw1, wa, 0, 0, 0);
        int kh = qh_ + 31 - t;
        #pragma unroll
        for (int rr = 0; rr < 4; ++rr) {
            if (kh >= 0 && kh < 32) relhS[(qrow + rr)*32 + kh] = ha[rr];
            int kw = qw_ + rr + 31 - t;
            if (kw >= 0 && kw < 32) relwS[(qrow + rr)*32 + kw] = wa[rr];
        }
    }

    float rw[4][2];
    #pragma unroll
    for (int rr = 0; rr < 4; ++rr)
        #pragma unroll
        for (int jp = 0; jp < 2; ++jp)
            rw[rr][jp] = relwS[(qrow + rr)*32 + jp*16 + lr];

    floatx4 o[4];
    #pragma unroll
    for (int ds = 0; ds < 4; ++ds) o[ds] = (floatx4){0.f,0.f,0.f,0.f};
    float lsum[4] = {0.f, 0.f, 0.f, 0.f};

    const float scale = 0.125f;

    for (int kt = 0; kt < 16; ++kt) {
        __syncthreads();
        *(short8*)((void*)(Ks + swz(sr, sc)))   = kreg0;
        *(short8*)((void*)(Ks + swz(sr, sc+1))) = kreg1;
        *(short8*)((void*)(Vs + swz(sr, sc)))   = vreg0;
        *(short8*)((void*)(Vs + swz(sr, sc+1))) = vreg1;
        __syncthreads();

        if (kt < 15) {
            const __hip_bfloat16* kk = kb + (size_t)(kt+1)*64*HD + (size_t)sr*HD + sc*8;
            kreg0 = *(const short8*)((const void*)kk);
            kreg1 = *(const short8*)((const void*)(kk + 8));
            const __hip_bfloat16* vv = vb + (size_t)sr*NTOK + (kt+1)*64 + sc*8;
            vreg0 = *(const short8*)((const void*)vv);
            vreg1 = *(const short8*)((const void*)(vv + 8));
        }

        float2 rh2[4];
        #pragma unroll
        for (int rr = 0; rr < 4; ++rr)
            rh2[rr] = *(const float2*)((const void*)(relhS + (qrow + rr)*32 + kt*2));

        floatx4 sv[4];
        #pragma unroll
        for (int j = 0; j < 4; ++j) {
            short8 kb0 = *(const short8*)((const void*)(Ks + swz(j*16 + lr, quad)));
            short8 kb1 = *(const short8*)((const void*)(Ks + swz(j*16 + lr, 4 + quad)));
            floatx4 z = (floatx4){0.f,0.f,0.f,0.f};
            z = __builtin_amdgcn_mfma_f32_16x16x32_bf16(qa0, kb0, z, 0, 0, 0);
            z = __builtin_amdgcn_mfma_f32_16x16x32_bf16(qa1, kb1, z, 0, 0, 0);
            sv[j] = z;
        }

        #pragma unroll
        for (int j = 0; j < 4; ++j) {
            int colc = j*2 + (lr >> 3);
            #pragma unroll
            for (int rr = 0; rr < 4; ++rr) {
                float s = sv[j][rr]*scale + ((j < 2) ? rh2[rr].x : rh2[rr].y) + rw[rr][j & 1];
                s = fminf(fmaxf(s, -60.f), 60.f);
                float pp = __expf(s);
                lsum[rr] += pp;
                int prow = quad*4 + rr;
                Ps[w*1024 + prow*64 + ((colc ^ (prow & 7)) << 3) + (lr & 7)] = __float2bfloat16(pp);
            }
        }

        short8 pa0 = *(const short8*)((const void*)(Ps + w*1024 + swz(lr, quad)));
        short8 pa1 = *(const short8*)((const void*)(Ps + w*1024 + swz(lr, 4 + quad)));
        #pragma unroll
        for (int ds = 0; ds < 4; ++ds) {
            short8 v0 = *(const short8*)((const void*)(Vs + swz(ds*16 + lr, quad)));
            short8 v1 = *(const short8*)((const void*)(Vs + swz(ds*16 + lr, 4 + quad)));
            o[ds] = __builtin_amdgcn_mfma_f32_16x16x32_bf16(pa0, v0, o[ds], 0, 0, 0);
            o[ds] = __builtin_amdgcn_mfma_f32_16x16x32_bf16(pa1, v1, o[ds], 0, 0, 0);
        }
    }

    #pragma unroll
    for (int off = 1; off < 16; off <<= 1)
        #pragma unroll
        for (int rr = 0; rr < 4; ++rr)
            lsum[rr] += __shfl_xor(lsum[rr], off, 16);

    #pragma unroll
    for (int rr = 0; rr < 4; ++rr) {
        float inv = 1.f / lsum[rr];
        int n = qt*64 + w*16 + quad*4 + rr;
        size_t base = ((size_t)b*NTOK + n)*EMBED + head*HD;
        #pragma unroll
        for (int ds = 0; ds < 4; ++ds)
            out[base + ds*16 + lr] = __float2bfloat16(o[ds][rr] * inv);
    }
}

extern "C" void kernel_launch(void* const* d_in, const int* in_sizes, int n_in,
                              void* d_out, int out_size, void* d_ws, size_t ws_size,
                              hipStream_t stream)
{
    const float* x      = (const float*)d_in[0];
    const float* conv_w = (const float*)d_in[1];
    const float* conv_b = (const float*)d_in[2];
    const float* pos    = (const float*)d_in[3];
    const float* ln1_w  = (const float*)d_in[4];
    const float* ln1_b  = (const float*)d_in[5];
    const float* qkv_w  = (const float*)d_in[6];
    const float* qkv_b  = (const float*)d_in[7];
    const float* proj_w = (const float*)d_in[8];
    const float* proj_b = (const float*)d_in[9];
    const float* rph    = (const float*)d_in[10];
    const float* rpw    = (const float*)d_in[11];
    const float* ln2_w  = (const float*)d_in[12];
    const float* ln2_b  = (const float*)d_in[13];
    const float* fc1_w  = (const float*)d_in[14];
    const float* fc1_b  = (const float*)d_in[15];
    const float* fc2_w  = (const float*)d_in[16];
    const float* fc2_b  = (const float*)d_in[17];

    // ws layout:
    //  h       fp32 [4096][768]                         12.58 MB
    //  scr     25.17 MB: qperm|kperm|vtperm|attn_o (bf16, each 6.29 MB)
    //          aliased after fc1 as p0|p1 (fp32 partials, each 12.58 MB)
    //  x_ln    bf16 [4096][768]                          6.29 MB
    //  mlp     bf16 [4096][3072] (also A_im)            25.17 MB
    //  weights qkv_wt|proj_wt|fc1_wt|fc2_wt (bf16)      14.16 MB
    char* p = (char*)d_ws;
    float*           h       = (float*)p;           p += (size_t)M_ROWS*EMBED*4;
    __hip_bfloat16*  q_perm  = (__hip_bfloat16*)p;
    float*           p0      = (float*)p;           p += (size_t)48*NTOK*HD*2;
    __hip_bfloat16*  k_perm  = (__hip_bfloat16*)p;  p += (size_t)48*NTOK*HD*2;
    __hip_bfloat16*  vt_perm = (__hip_bfloat16*)p;  p += (size_t)48*NTOK*HD*2;
    __hip_bfloat16*  attn_o  = (__hip_bfloat16*)p;  p += (size_t)M_ROWS*EMBED*2;
    __hip_bfloat16*  x_ln    = (__hip_bfloat16*)p;  p += (size_t)M_ROWS*EMBED*2;
    __hip_bfloat16*  mlp     = (__hip_bfloat16*)p;  p += (size_t)M_ROWS*MLPD*2;
    __hip_bfloat16*  qkv_wt  = (__hip_bfloat16*)p;  p += (size_t)2304*768*2;
    __hip_bfloat16*  proj_wt = (__hip_bfloat16*)p;  p += (size_t)768*768*2;
    __hip_bfloat16*  fc1_wt  = (__hip_bfloat16*)p;  p += (size_t)MLPD*768*2;
    __hip_bfloat16*  fc2_wt  = (__hip_bfloat16*)p;  p += (size_t)768*MLPD*2;

    __hip_bfloat16*  A_im    = mlp;      // alias: not simultaneously live
    __hip_bfloat16*  conv_wt = qkv_wt;   // alias: overwritten by layer-0 prep

    // ---- patch embed as GEMM (64x128 tiles) ----
    im2col<<<M_ROWS, 256, 0, stream>>>(x, A_im);
    cvt_bf16<<<(768*768 + 255)/256, 256, 0, stream>>>(conv_w, conv_wt, 768*768);
    gemm64<<<dim3(768/128, M_ROWS/64, 1), 256, 0, stream>>>(
        A_im, conv_wt, conv_b, nullptr, pos,
        h, nullptr, nullptr, nullptr, nullptr,
        M_ROWS, 768, 768, 1, 0, 0);

    layernorm_bf16<<<M_ROWS, 256, 0, stream>>>(h, ln1_w, ln1_b, x_ln);

    for (int L = 0; L < 4; ++L) {
        prep_weights<<<6912, 256, 0, stream>>>(
            qkv_w + (size_t)L*768*2304, proj_w + (size_t)L*768*768,
            fc1_w + (size_t)L*768*MLPD, fc2_w + (size_t)L*MLPD*768,
            qkv_wt, proj_wt, fc1_wt, fc2_wt);

        gemm64<<<dim3(2304/128, M_ROWS/64, 1), 256, 0, stream>>>(
            x_ln, qkv_wt, qkv_b + (size_t)L*3*EMBED, nullptr, nullptr,
            nullptr, nullptr, q_perm, k_perm, vt_perm,
            M_ROWS, 2304, 768, 1, 0, 2);

        attention_mfma<<<48*16, 256, 0, stream>>>(
            q_perm, k_perm, vt_perm,
            rph + (size_t)L*63*64, rpw + (size_t)L*63*64, attn_o);

        gemm64<<<dim3(768/128, M_ROWS/64, 1), 256, 0, stream>>>(
            attn_o, proj_wt, proj_b + (size_t)L*EMBED, h, nullptr,
            h, nullptr, nullptr, nullptr, nullptr,
            M_ROWS, 768, 768, 1, 0, 0);

        layernorm_bf16<<<M_ROWS, 256, 0, stream>>>(h, ln2_w + L*EMBED, ln2_b + L*EMBED, x_ln);

        gemm64<<<dim3(MLPD/128, M_ROWS/64, 1), 256, 0, stream>>>(
            x_ln, fc1_wt, fc1_b + (size_t)L*MLPD, nullptr, nullptr,
            nullptr, mlp, nullptr, nullptr, nullptr,
            M_ROWS, MLPD, 768, 1, 1, 1);

        // fc2 split-K=2 -> fp32 partials p0,p1 (alias dead q/k/vt/attn_o region)
        gemm64<<<dim3(768/128, M_ROWS/64, 2), 256, 0, stream>>>(
            mlp, fc2_wt, nullptr, nullptr, nullptr,
            p0, nullptr, nullptr, nullptr, nullptr,
            M_ROWS, 768, MLPD, 2, 0, 3);

        float* p1 = p0 + (size_t)M_ROWS*768;
        if (L < 3) {
            resum_ln<<<M_ROWS, 256, 0, stream>>>(
                h, p0, p1, fc2_b + (size_t)L*EMBED,
                ln1_w + (size_t)(L+1)*EMBED, ln1_b + (size_t)(L+1)*EMBED, x_ln);
        } else {
            resum_out<<<M_ROWS*EMBED/256, 256, 0, stream>>>(
                h, p0, p1, fc2_b + (size_t)L*EMBED, (float*)d_out);
        }
    }
}

// Round 7
// 1045.179 us; speedup vs baseline: 16.5792x; 1.0406x over previous
//
#include <hip/hip_runtime.h>
#include <hip/hip_bf16.h>
#include <math.h>
#include <stdint.h>

#define EMBED 768
#define NTOK  1024   // 32*32
#define BATCH 4
#define NHEAD 12
#define HD    64
#define MLPD  3072
#define M_ROWS 4096  // BATCH*NTOK

typedef __attribute__((ext_vector_type(8))) short short8;   // 8 x bf16 (4 VGPRs)
typedef __attribute__((ext_vector_type(4))) float floatx4;

__device__ __forceinline__ float b2f(__hip_bfloat16 v) { return __bfloat162float(v); }

// async global->LDS, 16B per lane (GEMM staging; layout lane-contiguous).
__device__ __forceinline__ void gld_lds16(const void* g, void* l) {
    __builtin_amdgcn_global_load_lds(
        (const __attribute__((address_space(1))) uint32_t*)g,
        (__attribute__((address_space(3))) uint32_t*)l, 16, 0, 0);
}

// XOR swizzle for attention tiles: chunk c (8 bf16) of row r at r*64 + ((c^(r&7))*8).
__device__ __forceinline__ int swz(int row, int c) { return row*64 + (((c) ^ (row & 7)) << 3); }

// ---------------- im2col: x (4,3,512,512) fp32 -> A_im (4096,768) bf16 --------------
__global__ __launch_bounds__(256)
void im2col(const float* __restrict__ x, __hip_bfloat16* __restrict__ A)
{
    int p  = blockIdx.x;
    int b  = p >> 10;
    int n  = p & 1023;
    int gh = n >> 5, gw = n & 31;
    int tid = threadIdx.x;
    for (int i = tid; i < 768; i += 256) {
        int ci = i >> 8, r = i & 255, kh = r >> 4, kw = r & 15;
        A[(size_t)p*768 + i] = __float2bfloat16(
            x[(((size_t)b*3 + ci)*512 + (gh*16 + kh))*512 + gw*16 + kw]);
    }
}

// ---------------- elementwise fp32 -> bf16 cast -------------------------------------
__global__ __launch_bounds__(256)
void cvt_bf16(const float* __restrict__ in, __hip_bfloat16* __restrict__ out, int n)
{
    int i = blockIdx.x*256 + threadIdx.x;
    if (i < n) out[i] = __float2bfloat16(in[i]);
}

// ---------------- layernorm: fp32 in -> bf16 out ------------------------------------
__global__ __launch_bounds__(256)
void layernorm_bf16(const float* __restrict__ in,
                    const float* __restrict__ w,
                    const float* __restrict__ b,
                    __hip_bfloat16* __restrict__ out)
{
    int row = blockIdx.x;
    const float* xr = in + (size_t)row*768;
    int tid = threadIdx.x;
    float v0 = xr[tid], v1 = xr[tid+256], v2 = xr[tid+512];
    float s = v0+v1+v2, ss = v0*v0+v1*v1+v2*v2;
    __shared__ float rs[256], rss[256];
    rs[tid] = s; rss[tid] = ss; __syncthreads();
    for (int o = 128; o > 0; o >>= 1) {
        if (tid < o) { rs[tid] += rs[tid+o]; rss[tid] += rss[tid+o]; }
        __syncthreads();
    }
    float mean = rs[0] * (1.f/768.f);
    float var  = rss[0] * (1.f/768.f) - mean*mean;
    float inv  = rsqrtf(var + 1e-5f);
    out[(size_t)row*768 + tid]     = __float2bfloat16((v0-mean)*inv*w[tid]     + b[tid]);
    out[(size_t)row*768 + tid+256] = __float2bfloat16((v1-mean)*inv*w[tid+256] + b[tid+256]);
    out[(size_t)row*768 + tid+512] = __float2bfloat16((v2-mean)*inv*w[tid+512] + b[tid+512]);
}

// ---------------- fused: h += p0+p1+bias ; x_ln = LN(h) (next layer ln1) ------------
__global__ __launch_bounds__(256)
void resum_ln(float* __restrict__ h,
              const float* __restrict__ p0, const float* __restrict__ p1,
              const float* __restrict__ bias,
              const float* __restrict__ w, const float* __restrict__ b,
              __hip_bfloat16* __restrict__ out)
{
    int row = blockIdx.x;
    int tid = threadIdx.x;
    size_t base = (size_t)row*768;
    float v[3];
    float s = 0.f, ss = 0.f;
    #pragma unroll
    for (int e = 0; e < 3; ++e) {
        int i = tid + e*256;
        float val = h[base+i] + p0[base+i] + p1[base+i] + bias[i];
        h[base+i] = val;
        v[e] = val; s += val; ss += val*val;
    }
    __shared__ float rs[256], rss[256];
    rs[tid] = s; rss[tid] = ss; __syncthreads();
    for (int o = 128; o > 0; o >>= 1) {
        if (tid < o) { rs[tid] += rs[tid+o]; rss[tid] += rss[tid+o]; }
        __syncthreads();
    }
    float mean = rs[0] * (1.f/768.f);
    float var  = rss[0] * (1.f/768.f) - mean*mean;
    float inv  = rsqrtf(var + 1e-5f);
    #pragma unroll
    for (int e = 0; e < 3; ++e) {
        int i = tid + e*256;
        out[base+i] = __float2bfloat16((v[e]-mean)*inv*w[i] + b[i]);
    }
}

// ---------------- final: out = h + p0 + p1 + bias (fp32) ----------------------------
__global__ __launch_bounds__(256)
void resum_out(const float* __restrict__ h,
               const float* __restrict__ p0, const float* __restrict__ p1,
               const float* __restrict__ bias,
               float* __restrict__ out)
{
    int i = blockIdx.x*256 + threadIdx.x;
    out[i] = h[i] + p0[i] + p1[i] + bias[i % 768];
}

// ---------------- merged weight prep: 4 transposes in one launch --------------------
__global__ __launch_bounds__(256)
void prep_weights(const float* __restrict__ qkv_w,  const float* __restrict__ proj_w,
                  const float* __restrict__ fc1_w,  const float* __restrict__ fc2_w,
                  __hip_bfloat16* __restrict__ qkv_wt, __hip_bfloat16* __restrict__ proj_wt,
                  __hip_bfloat16* __restrict__ fc1_wt, __hip_bfloat16* __restrict__ fc2_wt)
{
    int id = blockIdx.x;
    const float* src; __hip_bfloat16* dst; int K, N, bx, by;
    if (id < 1728)      {            src = qkv_w;  dst = qkv_wt;  K = 768;  N = 2304; bx = id % 72; by = id / 72; }
    else if (id < 2304) { id -= 1728; src = proj_w; dst = proj_wt; K = 768;  N = 768;  bx = id % 24; by = id / 24; }
    else if (id < 4608) { id -= 2304; src = fc1_w;  dst = fc1_wt;  K = 768;  N = 3072; bx = id % 96; by = id / 96; }
    else                { id -= 4608; src = fc2_w;  dst = fc2_wt;  K = 3072; N = 768;  bx = id % 24; by = id / 24; }

    __shared__ float t[32][33];
    int n0 = bx*32, k0 = by*32;
    int tx = threadIdx.x & 31, ty = threadIdx.x >> 5;   // (32, 8)
    #pragma unroll
    for (int r = 0; r < 4; ++r) {
        int row = ty + r*8;
        t[row][tx] = src[(size_t)(k0+row)*N + n0 + tx];
    }
    __syncthreads();
    #pragma unroll
    for (int r = 0; r < 4; ++r) {
        int row = ty + r*8;
        dst[(size_t)(n0+row)*K + k0 + tx] = __float2bfloat16(t[tx][row]);
    }
}

// ---------------- MFMA GEMM, 64x128 tile: C = epi(A[M,K] @ Bt[N,K]^T) ---------------
// grid (N/128, M/64, S). 4 waves 2x2: wave = 32 rows x 64 cols (2x4 mfma accs).
// emode 0: fp32 Cf (+res, +posadd) ; 1: bf16 Cb (+gelu), LDS-coalesced ;
// emode 2: qkv permute (LDS-coalesced) ; 3: fp32 partial -> Cf + z*M*N.
__global__ __launch_bounds__(256)
void gemm64(const __hip_bfloat16* __restrict__ A,
            const __hip_bfloat16* __restrict__ Bt,
            const float* __restrict__ bias,
            const float* __restrict__ res,
            const float* __restrict__ posadd,
            float* __restrict__ Cf,
            __hip_bfloat16* __restrict__ Cb,
            __hip_bfloat16* __restrict__ qp,
            __hip_bfloat16* __restrict__ kp,
            __hip_bfloat16* __restrict__ vp,
            int M, int N, int K, int S, int dogelu, int emode)
{
    // staging (12 KB) and epilogue scratch (4x5 KB) share one allocation
    __shared__ __align__(16) char smem[20480];
    __hip_bfloat16* As = (__hip_bfloat16*)smem;           // 64*32  (4 KB)
    __hip_bfloat16* Bs = (__hip_bfloat16*)(smem + 4096);  // 128*32 (8 KB)

    const int tid  = threadIdx.x;
    const int lane = tid & 63;
    const int wid  = tid >> 6;
    const int wr   = wid >> 1;          // 0..1 : 32-row half
    const int wc   = wid & 1;           // 0..1 : 64-col half
    const int lr   = lane & 15;
    const int quad = lane >> 4;

    const int bm = blockIdx.y * 64;
    const int bn = blockIdx.x * 128;
    const int z  = blockIdx.z;
    const int Kseg = K / S;
    const int kbeg = z * Kseg;
    const int kend = kbeg + Kseg;

    const int srow  = tid >> 2;         // 0..63
    const int skoff = (tid & 3) * 8;
    const int wbase = wid * 1024;       // bytes

    floatx4 acc[2][4];
    #pragma unroll
    for (int i = 0; i < 2; ++i)
        #pragma unroll
        for (int j = 0; j < 4; ++j)
            acc[i][j] = (floatx4){0.f,0.f,0.f,0.f};

    for (int k0 = kbeg; k0 < kend; k0 += 32) {
        gld_lds16(A + (size_t)(bm + srow)*K + k0 + skoff, (char*)As + wbase);
        #pragma unroll
        for (int c = 0; c < 2; ++c)
            gld_lds16(Bt + (size_t)(bn + c*64 + srow)*K + k0 + skoff,
                      (char*)Bs + c*4096 + wbase);
        __syncthreads();

        short8 a[2], b[4];
        #pragma unroll
        for (int i = 0; i < 2; ++i)
            a[i] = *(const short8*)((const void*)(As + (wr*32 + i*16 + lr)*32 + quad*8));
        #pragma unroll
        for (int j = 0; j < 4; ++j)
            b[j] = *(const short8*)((const void*)(Bs + (wc*64 + j*16 + lr)*32 + quad*8));
        #pragma unroll
        for (int i = 0; i < 2; ++i)
            #pragma unroll
            for (int j = 0; j < 4; ++j)
                acc[i][j] = __builtin_amdgcn_mfma_f32_16x16x32_bf16(a[i], b[j], acc[i][j], 0, 0, 0);
        __syncthreads();
    }
    // after the trailing barrier of the K-loop, smem is dead -> reuse per-wave

    if (emode == 2) {
        // ---- qkv permute, LDS-coalesced stores ----
        __hip_bfloat16* epi = (__hip_bfloat16*)(smem + wid*5120);
        const int head64 = (bn + wc*64) >> 6;     // wave's 64 cols = one head
        const int which  = head64 / 12;           // 0=q 1=k 2=v
        const int head   = head64 % 12;
        const int b_     = bm >> 10;
        const int bh     = b_*NHEAD + head;
        const int n0     = (bm + wr*32) & 1023;

        if (which < 2) {
            // [row32][col64], stride 72 bf16
            #pragma unroll
            for (int j = 0; j < 4; ++j) {
                float bs = bias[bn + wc*64 + j*16 + lr];
                #pragma unroll
                for (int i = 0; i < 2; ++i)
                    #pragma unroll
                    for (int r = 0; r < 4; ++r)
                        epi[(i*16 + quad*4 + r)*72 + j*16 + lr] =
                            __float2bfloat16(acc[i][j][r] + bs);
            }
            __hip_bfloat16* dst = (which == 0 ? qp : kp) + ((size_t)bh*NTOK + n0)*HD;
            #pragma unroll
            for (int p2 = 0; p2 < 4; ++p2) {
                int row = p2*8 + (lane >> 3), chunk = lane & 7;
                short8 v = *(const short8*)((const void*)(epi + row*72 + chunk*8));
                *(short8*)((void*)(dst + (size_t)row*HD + chunk*8)) = v;
            }
        } else {
            // transposed [col64][row32], stride 40 bf16
            #pragma unroll
            for (int j = 0; j < 4; ++j) {
                float bs = bias[bn + wc*64 + j*16 + lr];
                #pragma unroll
                for (int i = 0; i < 2; ++i)
                    #pragma unroll
                    for (int r = 0; r < 4; ++r)
                        epi[(j*16 + lr)*40 + i*16 + quad*4 + r] =
                            __float2bfloat16(acc[i][j][r] + bs);
            }
            __hip_bfloat16* dst = vp + (size_t)bh*HD*NTOK + n0;
            #pragma unroll
            for (int p2 = 0; p2 < 4; ++p2) {
                int d = p2*16 + (lane >> 2), chunk = lane & 3;
                short8 v = *(const short8*)((const void*)(epi + d*40 + chunk*8));
                *(short8*)((void*)(dst + (size_t)d*NTOK + chunk*8)) = v;
            }
        }
    } else if (emode == 1) {
        // ---- bf16 out (+gelu), LDS-coalesced stores ----
        __hip_bfloat16* epi = (__hip_bfloat16*)(smem + wid*5120);
        #pragma unroll
        for (int j = 0; j < 4; ++j) {
            float bs = bias[bn + wc*64 + j*16 + lr];
            #pragma unroll
            for (int i = 0; i < 2; ++i)
                #pragma unroll
                for (int r = 0; r < 4; ++r) {
                    float val = acc[i][j][r] + bs;
                    if (dogelu) val = 0.5f*val*(1.f + erff(val*0.70710678118f));
                    epi[(i*16 + quad*4 + r)*72 + j*16 + lr] = __float2bfloat16(val);
                }
        }
        #pragma unroll
        for (int p2 = 0; p2 < 4; ++p2) {
            int row = p2*8 + (lane >> 3), chunk = lane & 7;
            short8 v = *(const short8*)((const void*)(epi + row*72 + chunk*8));
            *(short8*)((void*)(Cb + (size_t)(bm + wr*32 + row)*N + bn + wc*64 + chunk*8)) = v;
        }
    } else {
        // ---- fp32 outputs (emode 0 / 3): direct 64B-chunk stores ----
        #pragma unroll
        for (int j = 0; j < 4; ++j) {
            int col = bn + wc*64 + j*16 + lr;
            float bs = (emode == 3) ? 0.f : bias[col];
            #pragma unroll
            for (int i = 0; i < 2; ++i) {
                #pragma unroll
                for (int r = 0; r < 4; ++r) {
                    int row = bm + wr*32 + i*16 + quad*4 + r;
                    float val = acc[i][j][r] + bs;
                    if (emode == 3) {
                        Cf[(size_t)z*M*N + (size_t)row*N + col] = val;
                    } else {
                        if (res)    val += res[(size_t)row*N + col];
                        if (posadd) val += posadd[(size_t)(row & 1023)*N + col];
                        Cf[(size_t)row*N + col] = val;
                    }
                }
            }
        }
    }
}

// ---------------- MFMA flash attention, swizzled LDS, shift-free softmax ------------
__global__ __launch_bounds__(256)
void attention_mfma(const __hip_bfloat16* __restrict__ qp,   // [48][1024][64]
                    const __hip_bfloat16* __restrict__ kp,   // [48][1024][64]
                    const __hip_bfloat16* __restrict__ vp,   // [48][64][1024] (V^T)
                    const float* __restrict__ rph,           // (63,64)
                    const float* __restrict__ rpw,           // (63,64)
                    __hip_bfloat16* __restrict__ out)        // (4,1024,768) bf16
{
    const int blk  = blockIdx.x;
    const int bh   = blk >> 4;
    const int qt   = blk & 15;
    const int b    = bh / NHEAD;
    const int head = bh % NHEAD;
    const int tid  = threadIdx.x;
    const int lane = tid & 63;
    const int w    = tid >> 6;
    const int lr   = lane & 15;
    const int quad = lane >> 4;

    __shared__ __align__(16) __hip_bfloat16 Qs[64*64];
    __shared__ __align__(16) __hip_bfloat16 Ks[64*64];      // prologue alias: rph table
    __shared__ __align__(16) __hip_bfloat16 Vs[64*64];      // prologue alias: rpw table
    __shared__ __align__(16) __hip_bfloat16 Ps[4*16*64];
    __shared__ float relhS[64*32];
    __shared__ float relwS[64*32];

    const __hip_bfloat16* qb = qp + ((size_t)bh*NTOK + qt*64)*HD;
    const __hip_bfloat16* kb = kp + (size_t)bh*NTOK*HD;
    const __hip_bfloat16* vb = vp + (size_t)bh*HD*NTOK;

    const int sr = tid >> 2;
    const int sc = (tid & 3) * 2;

    short8 kreg0, kreg1, vreg0, vreg1;
    {
        const __hip_bfloat16* kk = kb + (size_t)sr*HD + sc*8;
        kreg0 = *(const short8*)((const void*)kk);
        kreg1 = *(const short8*)((const void*)(kk + 8));
        const __hip_bfloat16* vv = vb + (size_t)sr*NTOK + sc*8;
        vreg0 = *(const short8*)((const void*)vv);
        vreg1 = *(const short8*)((const void*)(vv + 8));
    }

    {
        const __hip_bfloat16* qq = qb + (size_t)sr*HD + sc*8;
        short8 q0 = *(const short8*)((const void*)qq);
        short8 q1 = *(const short8*)((const void*)(qq + 8));
        *(short8*)((void*)(Qs + swz(sr, sc)))   = q0;
        *(short8*)((void*)(Qs + swz(sr, sc+1))) = q1;
    }

    for (int i = tid; i < 504; i += 256) {
        int r = i >> 3, c = i & 7;
        const float* ph = rph + (size_t)r*HD + c*8;
        const float* pw = rpw + (size_t)r*HD + c*8;
        union { short8 v; __hip_bfloat16 e[8]; } uh, uw;
        #pragma unroll
        for (int e = 0; e < 8; ++e) { uh.e[e] = __float2bfloat16(ph[e]); uw.e[e] = __float2bfloat16(pw[e]); }
        *(short8*)((void*)(Ks + swz(r, c))) = uh.v;
        *(short8*)((void*)(Vs + swz(r, c))) = uw.v;
    }
    if (tid < 16) {
        short8 z = (short8){0,0,0,0,0,0,0,0};
        int c = tid & 7;
        if (tid < 8) *(short8*)((void*)(Ks + swz(63, c))) = z;
        else         *(short8*)((void*)(Vs + swz(63, c))) = z;
    }
    __syncthreads();

    short8 qa0 = *(const short8*)((const void*)(Qs + swz(w*16 + lr, quad)));
    short8 qa1 = *(const short8*)((const void*)(Qs + swz(w*16 + lr, 4 + quad)));

    const int qrow = w*16 + quad*4;
    const int qh_  = qt*2 + (w >> 1);
    const int qw_  = (w & 1)*16 + quad*4;

    #pragma unroll
    for (int j = 0; j < 4; ++j) {
        int t = j*16 + lr;
        short8 th0 = *(const short8*)((const void*)(Ks + swz(j*16 + lr, quad)));
        short8 th1 = *(const short8*)((const void*)(Ks + swz(j*16 + lr, 4 + quad)));
        floatx4 ha = (floatx4){0.f,0.f,0.f,0.f};
        ha = __builtin_amdgcn_mfma_f32_16x16x32_bf16(qa0, th0, ha, 0, 0, 0);
        ha = __builtin_amdgcn_mfma_f32_16x16x32_bf16(qa1, th1, ha, 0, 0, 0);
        short8 tw0 = *(const short8*)((const void*)(Vs + swz(j*16 + lr, quad)));
        short8 tw1 = *(const short8*)((const void*)(Vs + swz(j*16 + lr, 4 + quad)));
        floatx4 wa = (floatx4){0.f,0.f,0.f,0.f};
        wa = __builtin_amdgcn_mfma_f32_16x16x32_bf16(qa0, tw0, wa, 0, 0, 0);
        wa = __builtin_amdgcn_mfma_f32_16x16x32_bf16(qa1, tw1, wa, 0, 0, 0);
        int kh = qh_ + 31 - t;
        #pragma unroll
        for (int rr = 0; rr < 4; ++rr) {
            if (kh >= 0 && kh < 32) relhS[(qrow + rr)*32 + kh] = ha[rr];
            int kw = qw_ + rr + 31 - t;
            if (kw >= 0 && kw < 32) relwS[(qrow + rr)*32 + kw] = wa[rr];
        }
    }

    float rw[4][2];
    #pragma unroll
    for (int rr = 0; rr < 4; ++rr)
        #pragma unroll
        for (int jp = 0; jp < 2; ++jp)
            rw[rr][jp] = relwS[(qrow + rr)*32 + jp*16 + lr];

    floatx4 o[4];
    #pragma unroll
    for (int ds = 0; ds < 4; ++ds) o[ds] = (floatx4){0.f,0.f,0.f,0.f};
    float lsum[4] = {0.f, 0.f, 0.f, 0.f};

    const float scale = 0.125f;

    for (int kt = 0; kt < 16; ++kt) {
        __syncthreads();
        *(short8*)((void*)(Ks + swz(sr, sc)))   = kreg0;
        *(short8*)((void*)(Ks + swz(sr, sc+1))) = kreg1;
        *(short8*)((void*)(Vs + swz(sr, sc)))   = vreg0;
        *(short8*)((void*)(Vs + swz(sr, sc+1))) = vreg1;
        __syncthreads();

        if (kt < 15) {
            const __hip_bfloat16* kk = kb + (size_t)(kt+1)*64*HD + (size_t)sr*HD + sc*8;
            kreg0 = *(const short8*)((const void*)kk);
            kreg1 = *(const short8*)((const void*)(kk + 8));
            const __hip_bfloat16* vv = vb + (size_t)sr*NTOK + (kt+1)*64 + sc*8;
            vreg0 = *(const short8*)((const void*)vv);
            vreg1 = *(const short8*)((const void*)(vv + 8));
        }

        float2 rh2[4];
        #pragma unroll
        for (int rr = 0; rr < 4; ++rr)
            rh2[rr] = *(const float2*)((const void*)(relhS + (qrow + rr)*32 + kt*2));

        floatx4 sv[4];
        #pragma unroll
        for (int j = 0; j < 4; ++j) {
            short8 kb0 = *(const short8*)((const void*)(Ks + swz(j*16 + lr, quad)));
            short8 kb1 = *(const short8*)((const void*)(Ks + swz(j*16 + lr, 4 + quad)));
            floatx4 z = (floatx4){0.f,0.f,0.f,0.f};
            z = __builtin_amdgcn_mfma_f32_16x16x32_bf16(qa0, kb0, z, 0, 0, 0);
            z = __builtin_amdgcn_mfma_f32_16x16x32_bf16(qa1, kb1, z, 0, 0, 0);
            sv[j] = z;
        }

        #pragma unroll
        for (int j = 0; j < 4; ++j) {
            int colc = j*2 + (lr >> 3);
            #pragma unroll
            for (int rr = 0; rr < 4; ++rr) {
                float s = sv[j][rr]*scale + ((j < 2) ? rh2[rr].x : rh2[rr].y) + rw[rr][j & 1];
                s = fminf(fmaxf(s, -60.f), 60.f);
                float pp = __expf(s);
                lsum[rr] += pp;
                int prow = quad*4 + rr;
                Ps[w*1024 + prow*64 + ((colc ^ (prow & 7)) << 3) + (lr & 7)] = __float2bfloat16(pp);
            }
        }

        short8 pa0 = *(const short8*)((const void*)(Ps + w*1024 + swz(lr, quad)));
        short8 pa1 = *(const short8*)((const void*)(Ps + w*1024 + swz(lr, 4 + quad)));
        #pragma unroll
        for (int ds = 0; ds < 4; ++ds) {
            short8 v0 = *(const short8*)((const void*)(Vs + swz(ds*16 + lr, quad)));
            short8 v1 = *(const short8*)((const void*)(Vs + swz(ds*16 + lr, 4 + quad)));
            o[ds] = __builtin_amdgcn_mfma_f32_16x16x32_bf16(pa0, v0, o[ds], 0, 0, 0);
            o[ds] = __builtin_amdgcn_mfma_f32_16x16x32_bf16(pa1, v1, o[ds], 0, 0, 0);
        }
    }

    #pragma unroll
    for (int off = 1; off < 16; off <<= 1)
        #pragma unroll
        for (int rr = 0; rr < 4; ++rr)
            lsum[rr] += __shfl_xor(lsum[rr], off, 16);

    #pragma unroll
    for (int rr = 0; rr < 4; ++rr) {
        float inv = 1.f / lsum[rr];
        int n = qt*64 + w*16 + quad*4 + rr;
        size_t base = ((size_t)b*NTOK + n)*EMBED + head*HD;
        #pragma unroll
        for (int ds = 0; ds < 4; ++ds)
            out[base + ds*16 + lr] = __float2bfloat16(o[ds][rr] * inv);
    }
}

extern "C" void kernel_launch(void* const* d_in, const int* in_sizes, int n_in,
                              void* d_out, int out_size, void* d_ws, size_t ws_size,
                              hipStream_t stream)
{
    const float* x      = (const float*)d_in[0];
    const float* conv_w = (const float*)d_in[1];
    const float* conv_b = (const float*)d_in[2];
    const float* pos    = (const float*)d_in[3];
    const float* ln1_w  = (const float*)d_in[4];
    const float* ln1_b  = (const float*)d_in[5];
    const float* qkv_w  = (const float*)d_in[6];
    const float* qkv_b  = (const float*)d_in[7];
    const float* proj_w = (const float*)d_in[8];
    const float* proj_b = (const float*)d_in[9];
    const float* rph    = (const float*)d_in[10];
    const float* rpw    = (const float*)d_in[11];
    const float* ln2_w  = (const float*)d_in[12];
    const float* ln2_b  = (const float*)d_in[13];
    const float* fc1_w  = (const float*)d_in[14];
    const float* fc1_b  = (const float*)d_in[15];
    const float* fc2_w  = (const float*)d_in[16];
    const float* fc2_b  = (const float*)d_in[17];

    char* p = (char*)d_ws;
    float*           h       = (float*)p;           p += (size_t)M_ROWS*EMBED*4;
    __hip_bfloat16*  q_perm  = (__hip_bfloat16*)p;
    float*           p0      = (float*)p;           p += (size_t)48*NTOK*HD*2;
    __hip_bfloat16*  k_perm  = (__hip_bfloat16*)p;  p += (size_t)48*NTOK*HD*2;
    __hip_bfloat16*  vt_perm = (__hip_bfloat16*)p;  p += (size_t)48*NTOK*HD*2;
    __hip_bfloat16*  attn_o  = (__hip_bfloat16*)p;  p += (size_t)M_ROWS*EMBED*2;
    __hip_bfloat16*  x_ln    = (__hip_bfloat16*)p;  p += (size_t)M_ROWS*EMBED*2;
    __hip_bfloat16*  mlp     = (__hip_bfloat16*)p;  p += (size_t)M_ROWS*MLPD*2;
    __hip_bfloat16*  qkv_wt  = (__hip_bfloat16*)p;  p += (size_t)2304*768*2;
    __hip_bfloat16*  proj_wt = (__hip_bfloat16*)p;  p += (size_t)768*768*2;
    __hip_bfloat16*  fc1_wt  = (__hip_bfloat16*)p;  p += (size_t)MLPD*768*2;
    __hip_bfloat16*  fc2_wt  = (__hip_bfloat16*)p;  p += (size_t)768*MLPD*2;

    __hip_bfloat16*  A_im    = mlp;      // alias: not simultaneously live
    __hip_bfloat16*  conv_wt = qkv_wt;   // alias: overwritten by layer-0 prep

    // ---- patch embed as GEMM (64x128 tiles) ----
    im2col<<<M_ROWS, 256, 0, stream>>>(x, A_im);
    cvt_bf16<<<(768*768 + 255)/256, 256, 0, stream>>>(conv_w, conv_wt, 768*768);
    gemm64<<<dim3(768/128, M_ROWS/64, 1), 256, 0, stream>>>(
        A_im, conv_wt, conv_b, nullptr, pos,
        h, nullptr, nullptr, nullptr, nullptr,
        M_ROWS, 768, 768, 1, 0, 0);

    layernorm_bf16<<<M_ROWS, 256, 0, stream>>>(h, ln1_w, ln1_b, x_ln);

    for (int L = 0; L < 4; ++L) {
        prep_weights<<<6912, 256, 0, stream>>>(
            qkv_w + (size_t)L*768*2304, proj_w + (size_t)L*768*768,
            fc1_w + (size_t)L*768*MLPD, fc2_w + (size_t)L*MLPD*768,
            qkv_wt, proj_wt, fc1_wt, fc2_wt);

        gemm64<<<dim3(2304/128, M_ROWS/64, 1), 256, 0, stream>>>(
            x_ln, qkv_wt, qkv_b + (size_t)L*3*EMBED, nullptr, nullptr,
            nullptr, nullptr, q_perm, k_perm, vt_perm,
            M_ROWS, 2304, 768, 1, 0, 2);

        attention_mfma<<<48*16, 256, 0, stream>>>(
            q_perm, k_perm, vt_perm,
            rph + (size_t)L*63*64, rpw + (size_t)L*63*64, attn_o);

        gemm64<<<dim3(768/128, M_ROWS/64, 1), 256, 0, stream>>>(
            attn_o, proj_wt, proj_b + (size_t)L*EMBED, h, nullptr,
            h, nullptr, nullptr, nullptr, nullptr,
            M_ROWS, 768, 768, 1, 0, 0);

        layernorm_bf16<<<M_ROWS, 256, 0, stream>>>(h, ln2_w + L*EMBED, ln2_b + L*EMBED, x_ln);

        gemm64<<<dim3(MLPD/128, M_ROWS/64, 1), 256, 0, stream>>>(
            x_ln, fc1_wt, fc1_b + (size_t)L*MLPD, nullptr, nullptr,
            nullptr, mlp, nullptr, nullptr, nullptr,
            M_ROWS, MLPD, 768, 1, 1, 1);

        // fc2 split-K=2 -> fp32 partials p0,p1 (alias dead q/k/vt/attn_o region)
        gemm64<<<dim3(768/128, M_ROWS/64, 2), 256, 0, stream>>>(
            mlp, fc2_wt, nullptr, nullptr, nullptr,
            p0, nullptr, nullptr, nullptr, nullptr,
            M_ROWS, 768, MLPD, 2, 0, 3);

        float* p1 = p0 + (size_t)M_ROWS*768;
        if (L < 3) {
            resum_ln<<<M_ROWS, 256, 0, stream>>>(
                h, p0, p1, fc2_b + (size_t)L*EMBED,
                ln1_w + (size_t)(L+1)*EMBED, ln1_b + (size_t)(L+1)*EMBED, x_ln);
        } else {
            resum_out<<<M_ROWS*EMBED/256, 256, 0, stream>>>(
                h, p0, p1, fc2_b + (size_t)L*EMBED, (float*)d_out);
        }
    }
}